// Round 6
// baseline (802.614 us; speedup 1.0000x reference)
//
#include <hip/hip_runtime.h>
#include <hip/hip_bf16.h>

// ---------------------------------------------------------------------------
// 2-layer GCN (PyG GCNConv semantics) on MI355X.
//   out[d] = relu( dinv[d]*( sum_e H'[src_e] + H'[d] ) + b ),  H' = dinv .* (X@W)
// R1->R2: CSR-gather instead of float atomics.
// R2->R3: device-wide 3-phase scan.
// R3->R4: register-tiled GEMM; packed edges.
// R4->R5: dinv factored into GEMM epilogue; src-only scatter.
// R5->R6: kill 64B/edge write-amp: dst-BIN (128 rows/bin) pipeline.
//   k_bin_scatter: block-local LDS counting sort by bin -> coalesced writes.
//   k_agg_bin: per-bin 128x64 LDS accumulator, ds_add_f32, fused epilogue.
//   (removes exact-CSR scan, k_scatter, k_gather_agg)
// ---------------------------------------------------------------------------

#define THREADS 256

// --- degree count ----------------------------------------------------------
__global__ void k_count_deg(const int* __restrict__ dst, int* __restrict__ degi,
                            int n_edges) {
    int e = blockIdx.x * blockDim.x + threadIdx.x;
    if (e < n_edges) atomicAdd(&degi[dst[e]], 1);
}

__global__ void k_make_dinv(const int* __restrict__ degi, float* __restrict__ dinv,
                            int n_nodes) {
    int i = blockIdx.x * blockDim.x + threadIdx.x;
    if (i < n_nodes) dinv[i] = 1.0f / sqrtf((float)(1 + degi[i]));
}

// --- bin counts (range-sums of degi) + exclusive scan + cursor init --------
// one block, 512 threads; nbins <= 512. bin b covers dst rows [b*128, b*128+128).
__global__ __launch_bounds__(512)
void k_bin_scan(const int* __restrict__ degi, int* __restrict__ bin_base,
                int* __restrict__ bincnt, int* __restrict__ bin_cursor,
                int n_nodes, int nbins) {
    __shared__ int s[512];
    int tid = threadIdx.x;
    int sum = 0;
    if (tid < nbins) {
        int i0 = tid << 7;
        int i1 = min(i0 + 128, n_nodes);
        for (int i = i0; i + 4 <= i1; i += 4) {
            int4 v = *(const int4*)&degi[i];
            sum += v.x + v.y + v.z + v.w;
        }
    }
    s[tid] = sum;
    __syncthreads();
    for (int ofs = 1; ofs < 512; ofs <<= 1) {
        int v = (tid >= ofs) ? s[tid - ofs] : 0;
        __syncthreads();
        s[tid] += v;
        __syncthreads();
    }
    if (tid < nbins) {
        int excl = s[tid] - sum;
        bin_base[tid] = excl;
        bincnt[tid] = sum;
        bin_cursor[tid] = excl;
    }
}

// --- binned scatter: block-local counting sort by bin, coalesced flush -----
// 512 threads x 8 edges = 4096 edges/block. packed = (src<<7) | (dst & 127).
__global__ __launch_bounds__(512)
void k_bin_scatter(const int* __restrict__ src, const int* __restrict__ dst,
                   int* __restrict__ bin_cursor, unsigned int* __restrict__ edge_binned,
                   int n_edges) {
    __shared__ int cnt[512];
    __shared__ int lbase[512];
    __shared__ int gbase[512];
    __shared__ int run[512];
    __shared__ unsigned int staged[4096];
    __shared__ unsigned short binarr[4096];
    const int tid = threadIdx.x;
    const int base = blockIdx.x * 4096 + tid * 8;
    cnt[tid] = 0;
    run[tid] = 0;
    __syncthreads();

    int dv[8], sv[8];
    int nv = (base < n_edges) ? min(8, n_edges - base) : 0;
    if (nv == 8) {
        int4 a = *(const int4*)&dst[base];
        int4 b = *(const int4*)&dst[base + 4];
        dv[0] = a.x; dv[1] = a.y; dv[2] = a.z; dv[3] = a.w;
        dv[4] = b.x; dv[5] = b.y; dv[6] = b.z; dv[7] = b.w;
        a = *(const int4*)&src[base];
        b = *(const int4*)&src[base + 4];
        sv[0] = a.x; sv[1] = a.y; sv[2] = a.z; sv[3] = a.w;
        sv[4] = b.x; sv[5] = b.y; sv[6] = b.z; sv[7] = b.w;
    } else {
        for (int j = 0; j < nv; ++j) {
            dv[j] = dst[base + j];
            sv[j] = src[base + j];
        }
    }
    for (int j = 0; j < nv; ++j) atomicAdd(&cnt[dv[j] >> 7], 1);
    __syncthreads();
    int mycnt = cnt[tid];
    // inclusive scan in place
    for (int ofs = 1; ofs < 512; ofs <<= 1) {
        int v = (tid >= ofs) ? cnt[tid - ofs] : 0;
        __syncthreads();
        cnt[tid] += v;
        __syncthreads();
    }
    lbase[tid] = cnt[tid] - mycnt;
    if (mycnt > 0) gbase[tid] = atomicAdd(&bin_cursor[tid], mycnt);
    __syncthreads();
    for (int j = 0; j < nv; ++j) {
        int bn = dv[j] >> 7;
        int rank = atomicAdd(&run[bn], 1);
        int lp = lbase[bn] + rank;
        staged[lp] = ((unsigned)sv[j] << 7) | (unsigned)(dv[j] & 127);
        binarr[lp] = (unsigned short)bn;
    }
    __syncthreads();
    int tot = cnt[511];
    for (int slot = tid; slot < tot; slot += 512) {
        int bn = binarr[slot];
        edge_binned[gbase[bn] + (slot - lbase[bn])] = staged[slot];
    }
}

// --- register-tiled GEMM: H'[r,:] = dinv[r] * (X[r,:K] @ W[K,64]) ----------
template <int K>
__global__ __launch_bounds__(256, 2)
void k_gemm(const float* __restrict__ X, const float* __restrict__ W,
            const float* __restrict__ dinv, float* __restrict__ H, int n_rows) {
    constexpr int KQ = K / 4;
    constexpr int RSH = (KQ == 32) ? 5 : 4;
    __shared__ float sW[K * 64];
    __shared__ float sX[64 * K];
    const int tid = threadIdx.x;
    const int row0 = blockIdx.x * 64;

#pragma unroll
    for (int it = 0; it < (K * 64 / 4) / THREADS; ++it) {
        int idx = it * THREADS + tid;
        ((float4*)sW)[idx] = ((const float4*)W)[idx];
    }
#pragma unroll
    for (int it = 0; it < (64 * KQ) / THREADS; ++it) {
        int idx = it * THREADS + tid;
        int kq = idx & (KQ - 1);
        int r = idx >> RSH;
        float4 g = make_float4(0.f, 0.f, 0.f, 0.f);
        int grow = row0 + r;
        if (grow < n_rows) g = *(const float4*)&X[(size_t)grow * K + 4 * kq];
        *(float4*)&sX[r * K + ((kq ^ (r & 7)) << 2)] = g;
    }
    __syncthreads();

    const int tx = tid & 15;
    const int ty = tid >> 4;
    float acc[4][4];
#pragma unroll
    for (int i = 0; i < 4; ++i)
#pragma unroll
        for (int j = 0; j < 4; ++j) acc[i][j] = 0.f;

#pragma unroll 2
    for (int k4 = 0; k4 < KQ; ++k4) {
        float4 b0 = *(const float4*)&sW[(4 * k4 + 0) * 64 + 4 * tx];
        float4 b1 = *(const float4*)&sW[(4 * k4 + 1) * 64 + 4 * tx];
        float4 b2 = *(const float4*)&sW[(4 * k4 + 2) * 64 + 4 * tx];
        float4 b3 = *(const float4*)&sW[(4 * k4 + 3) * 64 + 4 * tx];
#pragma unroll
        for (int i = 0; i < 4; ++i) {
            int r = 4 * ty + i;
            float4 a = *(const float4*)&sX[r * K + ((k4 ^ (r & 7)) << 2)];
            acc[i][0] = fmaf(a.x, b0.x, acc[i][0]);
            acc[i][1] = fmaf(a.x, b0.y, acc[i][1]);
            acc[i][2] = fmaf(a.x, b0.z, acc[i][2]);
            acc[i][3] = fmaf(a.x, b0.w, acc[i][3]);
            acc[i][0] = fmaf(a.y, b1.x, acc[i][0]);
            acc[i][1] = fmaf(a.y, b1.y, acc[i][1]);
            acc[i][2] = fmaf(a.y, b1.z, acc[i][2]);
            acc[i][3] = fmaf(a.y, b1.w, acc[i][3]);
            acc[i][0] = fmaf(a.z, b2.x, acc[i][0]);
            acc[i][1] = fmaf(a.z, b2.y, acc[i][1]);
            acc[i][2] = fmaf(a.z, b2.z, acc[i][2]);
            acc[i][3] = fmaf(a.z, b2.w, acc[i][3]);
            acc[i][0] = fmaf(a.w, b3.x, acc[i][0]);
            acc[i][1] = fmaf(a.w, b3.y, acc[i][1]);
            acc[i][2] = fmaf(a.w, b3.z, acc[i][2]);
            acc[i][3] = fmaf(a.w, b3.w, acc[i][3]);
        }
    }

#pragma unroll
    for (int i = 0; i < 4; ++i) {
        int grow = row0 + 4 * ty + i;
        if (grow < n_rows) {
            float dvv = dinv[grow];
            float4 o = make_float4(acc[i][0] * dvv, acc[i][1] * dvv,
                                   acc[i][2] * dvv, acc[i][3] * dvv);
            *(float4*)&H[(size_t)grow * 64 + 4 * tx] = o;
        }
    }
}

// --- per-bin aggregate: LDS accumulator + ds_add_f32, fused epilogue -------
// one block per bin; acc[128][64] in LDS (32KB). 4 waves stream the bin's
// packed edges; 64 lanes gather one H' row and atomically add into the tile.
__global__ __launch_bounds__(256)
void k_agg_bin(const float* __restrict__ Hp, const unsigned int* __restrict__ eb,
               const int* __restrict__ bin_base, const int* __restrict__ bincnt,
               const float* __restrict__ dinv, const float* __restrict__ bias,
               float* __restrict__ out, int n_nodes) {
    __shared__ float acc[128 * 64];
    const int tid = threadIdx.x;
#pragma unroll
    for (int i = 0; i < 8; ++i)
        ((float4*)acc)[i * 256 + tid] = make_float4(0.f, 0.f, 0.f, 0.f);
    __syncthreads();

    const int b = blockIdx.x;
    const int node0 = b << 7;
    const int ebeg = bin_base[b];
    const int ecnt = bincnt[b];
    const int lane = tid & 63;
    const int wid = tid >> 6;

    int per = (ecnt + 3) >> 2;
    int s = ebeg + wid * per;
    int e = min(s + per, ebeg + ecnt);
    int k = s;
    for (; k + 8 <= e; k += 8) {
        unsigned p0 = eb[k + 0], p1 = eb[k + 1], p2 = eb[k + 2], p3 = eb[k + 3];
        unsigned p4 = eb[k + 4], p5 = eb[k + 5], p6 = eb[k + 6], p7 = eb[k + 7];
        float v0 = Hp[((size_t)(p0 >> 7) << 6) + lane];
        float v1 = Hp[((size_t)(p1 >> 7) << 6) + lane];
        float v2 = Hp[((size_t)(p2 >> 7) << 6) + lane];
        float v3 = Hp[((size_t)(p3 >> 7) << 6) + lane];
        float v4 = Hp[((size_t)(p4 >> 7) << 6) + lane];
        float v5 = Hp[((size_t)(p5 >> 7) << 6) + lane];
        float v6 = Hp[((size_t)(p6 >> 7) << 6) + lane];
        float v7 = Hp[((size_t)(p7 >> 7) << 6) + lane];
        atomicAdd(&acc[((p0 & 127u) << 6) + lane], v0);
        atomicAdd(&acc[((p1 & 127u) << 6) + lane], v1);
        atomicAdd(&acc[((p2 & 127u) << 6) + lane], v2);
        atomicAdd(&acc[((p3 & 127u) << 6) + lane], v3);
        atomicAdd(&acc[((p4 & 127u) << 6) + lane], v4);
        atomicAdd(&acc[((p5 & 127u) << 6) + lane], v5);
        atomicAdd(&acc[((p6 & 127u) << 6) + lane], v6);
        atomicAdd(&acc[((p7 & 127u) << 6) + lane], v7);
    }
    for (; k < e; ++k) {
        unsigned p = eb[k];
        atomicAdd(&acc[((p & 127u) << 6) + lane], Hp[((size_t)(p >> 7) << 6) + lane]);
    }
    __syncthreads();

    const int rows = min(128, n_nodes - node0);
    for (int i = tid; i < rows * 16; i += 256) {
        int r = i >> 4;
        int c = i & 15;
        int node = node0 + r;
        float dvv = dinv[node];
        float4 a = ((const float4*)acc)[(r << 4) + c];
        float4 hh = ((const float4*)(Hp + ((size_t)node << 6)))[c];
        float4 bb = ((const float4*)bias)[c];
        float4 o;
        o.x = fmaxf(fmaf(a.x + hh.x, dvv, bb.x), 0.f);
        o.y = fmaxf(fmaf(a.y + hh.y, dvv, bb.y), 0.f);
        o.z = fmaxf(fmaf(a.z + hh.z, dvv, bb.z), 0.f);
        o.w = fmaxf(fmaf(a.w + hh.w, dvv, bb.w), 0.f);
        ((float4*)(out + ((size_t)node << 6)))[c] = o;
    }
}

extern "C" void kernel_launch(void* const* d_in, const int* in_sizes, int n_in,
                              void* d_out, int out_size, void* d_ws, size_t ws_size,
                              hipStream_t stream) {
    const float* x  = (const float*)d_in[0];
    const int*   ei = (const int*)d_in[1];   // [2, E] int32
    const float* W1 = (const float*)d_in[2];
    const float* b1 = (const float*)d_in[3];
    const float* W2 = (const float*)d_in[4];
    const float* b2 = (const float*)d_in[5];
    float* out = (float*)d_out;

    const int n_feat  = 128;
    const int n_nodes = in_sizes[0] / n_feat;   // 50000
    const int n_edges = in_sizes[1] / 2;        // 800000
    const int* src = ei;
    const int* dst = ei + n_edges;
    const int nbins = (n_nodes + 127) >> 7;     // 391 (<= 512)

    // workspace layout (4B units, 16B-aligned chunks)
    const size_t n_pad = (size_t)((n_nodes + 63) & ~63);
    float* dinv        = (float*)d_ws;                   // n_pad
    int*   degi        = (int*)(dinv + n_pad);           // n_pad
    int*   bin_base    = degi + n_pad;                   // 512
    int*   bincnt      = bin_base + 512;                 // 512
    int*   bin_cursor  = bincnt + 512;                   // 512
    unsigned int* edge_binned = (unsigned int*)(bin_cursor + 512);   // e_pad
    const size_t e_pad = (size_t)((n_edges + 63) & ~63);
    float* h           = (float*)(edge_binned + e_pad);  // n_nodes*64

    // ---- preprocessing (once per call; reused by both layers) ----
    hipMemsetAsync(degi, 0, n_pad * sizeof(int), stream);
    k_count_deg<<<(n_edges + THREADS - 1) / THREADS, THREADS, 0, stream>>>(dst, degi, n_edges);
    k_make_dinv<<<(n_nodes + THREADS - 1) / THREADS, THREADS, 0, stream>>>(degi, dinv, n_nodes);
    k_bin_scan<<<1, 512, 0, stream>>>(degi, bin_base, bincnt, bin_cursor, n_nodes, nbins);
    k_bin_scatter<<<(n_edges + 4095) / 4096, 512, 0, stream>>>(
        src, dst, bin_cursor, edge_binned, n_edges);

    const int gemm_blocks = (n_nodes + 63) / 64;

    // ---- layer 1 ----
    k_gemm<128><<<gemm_blocks, THREADS, 0, stream>>>(x, W1, dinv, h, n_nodes);
    k_agg_bin<<<nbins, THREADS, 0, stream>>>(
        h, edge_binned, bin_base, bincnt, dinv, b1, out, n_nodes);

    // ---- layer 2 ----
    k_gemm<64><<<gemm_blocks, THREADS, 0, stream>>>(out, W2, dinv, h, n_nodes);
    k_agg_bin<<<nbins, THREADS, 0, stream>>>(
        h, edge_binned, bin_base, bincnt, dinv, b2, out, n_nodes);
}

// Round 7
// 166.116 us; speedup vs baseline: 4.8317x; 4.8317x over previous
//
#include <hip/hip_runtime.h>
#include <hip/hip_bf16.h>

// ---------------------------------------------------------------------------
// 2-layer GCN (PyG GCNConv semantics) on MI355X.
//   out[d] = relu( dinv[d]*( sum_e H'[src_e] + H'[d] ) + b ),  H' = dinv .* (X@W)
// R1->R2: CSR-gather instead of float atomics.
// R2->R3: device-wide 3-phase scan.
// R3->R4: register-tiled GEMM.
// R4->R5: dinv factored into GEMM epilogue; per-node gather 16 lanes x float4.
// R5->R6: binned LDS-accumulate agg -- REGRESSED (4 waves/CU, latency-bound).
// R6->R7: keep R5 gather; fix scatter write-amp with two-pass binning:
//   pass1 k_bin_scatter: LDS counting-sort by 64-row bin -> coalesced writes.
//   pass2 k_csr_scatter: per-bin LDS node-cursors -> exact CSR within a 4KB
//   window per block (write-merge in one XCD's L2).
// ---------------------------------------------------------------------------

#define THREADS 256

// --- degree count ----------------------------------------------------------
__global__ void k_count_deg(const int* __restrict__ dst, int* __restrict__ degi,
                            int n_edges) {
    int e = blockIdx.x * blockDim.x + threadIdx.x;
    if (e < n_edges) atomicAdd(&degi[dst[e]], 1);
}

__global__ void k_make_dinv(const int* __restrict__ degi, float* __restrict__ dinv,
                            int n_nodes) {
    int i = blockIdx.x * blockDim.x + threadIdx.x;
    if (i < n_nodes) dinv[i] = 1.0f / sqrtf((float)(1 + degi[i]));
}

// --- 3-phase device-wide exclusive scan ------------------------------------
__global__ void k_scan_partial(const int* __restrict__ degi, int* __restrict__ block_sums,
                               int n_nodes) {
    __shared__ int red[THREADS];
    int i = blockIdx.x * THREADS + threadIdx.x;
    red[threadIdx.x] = (i < n_nodes) ? degi[i] : 0;
    __syncthreads();
    for (int ofs = THREADS >> 1; ofs > 0; ofs >>= 1) {
        if (threadIdx.x < ofs) red[threadIdx.x] += red[threadIdx.x + ofs];
        __syncthreads();
    }
    if (threadIdx.x == 0) block_sums[blockIdx.x] = red[0];
}

__global__ void k_scan_blocks(int* __restrict__ block_sums, int n_blocks) {
    __shared__ int s[THREADS];
    int tid = threadIdx.x;
    s[tid] = (tid < n_blocks) ? block_sums[tid] : 0;
    __syncthreads();
    for (int ofs = 1; ofs < THREADS; ofs <<= 1) {
        int v = (tid >= ofs) ? s[tid - ofs] : 0;
        __syncthreads();
        s[tid] += v;
        __syncthreads();
    }
    if (tid < n_blocks) block_sums[tid] = (tid > 0) ? s[tid - 1] : 0;
}

// offsets[i] = exclusive prefix of degi; also init 64-row bin cursors.
__global__ void k_scan_final(const int* __restrict__ degi, const int* __restrict__ block_sums,
                             int* __restrict__ offsets, int* __restrict__ bin_cursor,
                             int n_nodes) {
    __shared__ int s[THREADS];
    int tid = threadIdx.x;
    int i = blockIdx.x * THREADS + tid;
    int v = (i < n_nodes) ? degi[i] : 0;
    s[tid] = v;
    __syncthreads();
    for (int ofs = 1; ofs < THREADS; ofs <<= 1) {
        int t = (tid >= ofs) ? s[tid - ofs] : 0;
        __syncthreads();
        s[tid] += t;
        __syncthreads();
    }
    int excl = s[tid] - v + block_sums[blockIdx.x];
    if (i < n_nodes) {
        offsets[i] = excl;
        if ((i & 63) == 0) bin_cursor[i >> 6] = excl;
    }
}

// --- pass 1: bin edges by 64-row dst-bin, coalesced writes -----------------
// 1024 threads x 4 edges = 4096 edges/block. packed = (src<<6) | (dst & 63).
__global__ __launch_bounds__(1024)
void k_bin_scatter(const int* __restrict__ src, const int* __restrict__ dst,
                   int* __restrict__ bin_cursor, unsigned int* __restrict__ edge_binned,
                   int n_edges) {
    __shared__ int cnt[1024];
    __shared__ int lbase[1024];
    __shared__ int gbase[1024];
    __shared__ int run[1024];
    __shared__ unsigned int staged[4096];
    __shared__ unsigned short binarr[4096];
    const int tid = threadIdx.x;
    const int base = blockIdx.x * 4096 + tid * 4;
    cnt[tid] = 0;
    run[tid] = 0;
    __syncthreads();

    int dv[4], sv[4];
    int nv = (base < n_edges) ? min(4, n_edges - base) : 0;
    if (nv == 4) {
        int4 a = *(const int4*)&dst[base];
        dv[0] = a.x; dv[1] = a.y; dv[2] = a.z; dv[3] = a.w;
        int4 b = *(const int4*)&src[base];
        sv[0] = b.x; sv[1] = b.y; sv[2] = b.z; sv[3] = b.w;
    } else {
        for (int j = 0; j < nv; ++j) {
            dv[j] = dst[base + j];
            sv[j] = src[base + j];
        }
    }
    for (int j = 0; j < nv; ++j) atomicAdd(&cnt[dv[j] >> 6], 1);
    __syncthreads();
    int mycnt = cnt[tid];
    for (int ofs = 1; ofs < 1024; ofs <<= 1) {   // inclusive scan in place
        int v = (tid >= ofs) ? cnt[tid - ofs] : 0;
        __syncthreads();
        cnt[tid] += v;
        __syncthreads();
    }
    lbase[tid] = cnt[tid] - mycnt;
    if (mycnt > 0) gbase[tid] = atomicAdd(&bin_cursor[tid], mycnt);
    __syncthreads();
    for (int j = 0; j < nv; ++j) {
        int bn = dv[j] >> 6;
        int rank = atomicAdd(&run[bn], 1);
        int lp = lbase[bn] + rank;
        staged[lp] = ((unsigned)sv[j] << 6) | (unsigned)(dv[j] & 63);
        binarr[lp] = (unsigned short)bn;
    }
    __syncthreads();
    int tot = cnt[1023];
    for (int slot = tid; slot < tot; slot += 1024) {
        int bn = binarr[slot];
        edge_binned[gbase[bn] + (slot - lbase[bn])] = staged[slot];
    }
}

// --- pass 2: binned -> exact CSR (one block per 64-row bin) ----------------
__global__ __launch_bounds__(256)
void k_csr_scatter(const unsigned int* __restrict__ edge_binned,
                   const int* __restrict__ offsets, int* __restrict__ edge_src,
                   int n_nodes, int n_edges) {
    __shared__ int lcur[64];
    const int b = blockIdx.x;
    const int node0 = b << 6;
    const int tid = threadIdx.x;
    if (tid < 64) {
        int node = node0 + tid;
        lcur[tid] = (node < n_nodes) ? offsets[node] : n_edges;
    }
    __syncthreads();
    int ebeg = offsets[node0];
    int node_end = node0 + 64;
    int eend = (node_end < n_nodes) ? offsets[node_end] : n_edges;
    for (int k = ebeg + tid; k < eend; k += 256) {
        unsigned p = edge_binned[k];
        int row = (int)(p & 63u);
        int pos = atomicAdd(&lcur[row], 1);
        edge_src[pos] = (int)(p >> 6);
    }
}

// --- register-tiled GEMM: H'[r,:] = dinv[r] * (X[r,:K] @ W[K,64]) ----------
template <int K>
__global__ __launch_bounds__(256, 2)
void k_gemm(const float* __restrict__ X, const float* __restrict__ W,
            const float* __restrict__ dinv, float* __restrict__ H, int n_rows) {
    constexpr int KQ = K / 4;
    constexpr int RSH = (KQ == 32) ? 5 : 4;
    __shared__ float sW[K * 64];
    __shared__ float sX[64 * K];
    const int tid = threadIdx.x;
    const int row0 = blockIdx.x * 64;

#pragma unroll
    for (int it = 0; it < (K * 64 / 4) / THREADS; ++it) {
        int idx = it * THREADS + tid;
        ((float4*)sW)[idx] = ((const float4*)W)[idx];
    }
#pragma unroll
    for (int it = 0; it < (64 * KQ) / THREADS; ++it) {
        int idx = it * THREADS + tid;
        int kq = idx & (KQ - 1);
        int r = idx >> RSH;
        float4 g = make_float4(0.f, 0.f, 0.f, 0.f);
        int grow = row0 + r;
        if (grow < n_rows) g = *(const float4*)&X[(size_t)grow * K + 4 * kq];
        *(float4*)&sX[r * K + ((kq ^ (r & 7)) << 2)] = g;
    }
    __syncthreads();

    const int tx = tid & 15;
    const int ty = tid >> 4;
    float acc[4][4];
#pragma unroll
    for (int i = 0; i < 4; ++i)
#pragma unroll
        for (int j = 0; j < 4; ++j) acc[i][j] = 0.f;

#pragma unroll 2
    for (int k4 = 0; k4 < KQ; ++k4) {
        float4 b0 = *(const float4*)&sW[(4 * k4 + 0) * 64 + 4 * tx];
        float4 b1 = *(const float4*)&sW[(4 * k4 + 1) * 64 + 4 * tx];
        float4 b2 = *(const float4*)&sW[(4 * k4 + 2) * 64 + 4 * tx];
        float4 b3 = *(const float4*)&sW[(4 * k4 + 3) * 64 + 4 * tx];
#pragma unroll
        for (int i = 0; i < 4; ++i) {
            int r = 4 * ty + i;
            float4 a = *(const float4*)&sX[r * K + ((k4 ^ (r & 7)) << 2)];
            acc[i][0] = fmaf(a.x, b0.x, acc[i][0]);
            acc[i][1] = fmaf(a.x, b0.y, acc[i][1]);
            acc[i][2] = fmaf(a.x, b0.z, acc[i][2]);
            acc[i][3] = fmaf(a.x, b0.w, acc[i][3]);
            acc[i][0] = fmaf(a.y, b1.x, acc[i][0]);
            acc[i][1] = fmaf(a.y, b1.y, acc[i][1]);
            acc[i][2] = fmaf(a.y, b1.z, acc[i][2]);
            acc[i][3] = fmaf(a.y, b1.w, acc[i][3]);
            acc[i][0] = fmaf(a.z, b2.x, acc[i][0]);
            acc[i][1] = fmaf(a.z, b2.y, acc[i][1]);
            acc[i][2] = fmaf(a.z, b2.z, acc[i][2]);
            acc[i][3] = fmaf(a.z, b2.w, acc[i][3]);
            acc[i][0] = fmaf(a.w, b3.x, acc[i][0]);
            acc[i][1] = fmaf(a.w, b3.y, acc[i][1]);
            acc[i][2] = fmaf(a.w, b3.z, acc[i][2]);
            acc[i][3] = fmaf(a.w, b3.w, acc[i][3]);
        }
    }

#pragma unroll
    for (int i = 0; i < 4; ++i) {
        int grow = row0 + 4 * ty + i;
        if (grow < n_rows) {
            float dvv = dinv[grow];
            float4 o = make_float4(acc[i][0] * dvv, acc[i][1] * dvv,
                                   acc[i][2] * dvv, acc[i][3] * dvv);
            *(float4*)&H[(size_t)grow * 64 + 4 * tx] = o;
        }
    }
}

// --- gather-aggregate + fused epilogue (R5, measured-fast) ------------------
// 16 lanes x float4 per node, 4 nodes per wave:
//   out[d,:] = relu( dinv[d] * ( sum_e H'[src_e,:] + H'[d,:] ) + b )
__global__ void k_gather_agg(const float* __restrict__ Hp, const int* __restrict__ offsets,
                             const int* __restrict__ degi, const int* __restrict__ edge_src,
                             const float* __restrict__ dinv, const float* __restrict__ b,
                             float* __restrict__ out, int n_nodes) {
    int node = blockIdx.x * (THREADS / 16) + (threadIdx.x >> 4);
    if (node >= n_nodes) return;
    int l = threadIdx.x & 15;            // float4 slot: feats 4l..4l+3
    int start = offsets[node];
    int cnt = degi[node];

    float4 acc = ((const float4*)(Hp + (size_t)node * 64))[l];   // self term

    int k = 0;
    for (; k + 4 <= cnt; k += 4) {
        int s0 = edge_src[start + k];
        int s1 = edge_src[start + k + 1];
        int s2 = edge_src[start + k + 2];
        int s3 = edge_src[start + k + 3];
        float4 v0 = ((const float4*)(Hp + (size_t)s0 * 64))[l];
        float4 v1 = ((const float4*)(Hp + (size_t)s1 * 64))[l];
        float4 v2 = ((const float4*)(Hp + (size_t)s2 * 64))[l];
        float4 v3 = ((const float4*)(Hp + (size_t)s3 * 64))[l];
        acc.x += v0.x + v1.x + v2.x + v3.x;
        acc.y += v0.y + v1.y + v2.y + v3.y;
        acc.z += v0.z + v1.z + v2.z + v3.z;
        acc.w += v0.w + v1.w + v2.w + v3.w;
    }
    for (; k < cnt; ++k) {
        int s0 = edge_src[start + k];
        float4 v0 = ((const float4*)(Hp + (size_t)s0 * 64))[l];
        acc.x += v0.x;
        acc.y += v0.y;
        acc.z += v0.z;
        acc.w += v0.w;
    }

    float dv = dinv[node];
    float4 bb = ((const float4*)b)[l];
    float4 o;
    o.x = fmaxf(fmaf(acc.x, dv, bb.x), 0.0f);
    o.y = fmaxf(fmaf(acc.y, dv, bb.y), 0.0f);
    o.z = fmaxf(fmaf(acc.z, dv, bb.z), 0.0f);
    o.w = fmaxf(fmaf(acc.w, dv, bb.w), 0.0f);
    ((float4*)(out + (size_t)node * 64))[l] = o;
}

extern "C" void kernel_launch(void* const* d_in, const int* in_sizes, int n_in,
                              void* d_out, int out_size, void* d_ws, size_t ws_size,
                              hipStream_t stream) {
    const float* x  = (const float*)d_in[0];
    const int*   ei = (const int*)d_in[1];   // [2, E] int32
    const float* W1 = (const float*)d_in[2];
    const float* b1 = (const float*)d_in[3];
    const float* W2 = (const float*)d_in[4];
    const float* b2 = (const float*)d_in[5];
    float* out = (float*)d_out;

    const int n_feat  = 128;
    const int n_nodes = in_sizes[0] / n_feat;   // 50000
    const int n_edges = in_sizes[1] / 2;        // 800000
    const int* src = ei;
    const int* dst = ei + n_edges;
    const int nbins = (n_nodes + 63) >> 6;      // 782 (<= 1024)
    const int scan_blocks = (n_nodes + THREADS - 1) / THREADS;   // 196 (<= 256)

    // workspace layout (4B units, 16B-aligned chunks)
    const size_t n_pad = (size_t)((n_nodes + 63) & ~63);
    float* dinv        = (float*)d_ws;                   // n_pad
    int*   degi        = (int*)(dinv + n_pad);           // n_pad
    int*   offsets     = degi + n_pad;                   // n_pad
    int*   block_sums  = offsets + n_pad;                // 256
    int*   bin_cursor  = block_sums + 256;               // 1024
    const size_t e_pad = (size_t)((n_edges + 63) & ~63);
    unsigned int* edge_binned = (unsigned int*)(bin_cursor + 1024);  // e_pad
    int*   edge_src    = (int*)(edge_binned + e_pad);    // e_pad
    float* h           = (float*)(edge_src + e_pad);     // n_nodes*64

    // ---- preprocessing (once per call; reused by both layers) ----
    hipMemsetAsync(degi, 0, n_pad * sizeof(int), stream);
    k_count_deg<<<(n_edges + THREADS - 1) / THREADS, THREADS, 0, stream>>>(dst, degi, n_edges);
    k_make_dinv<<<(n_nodes + THREADS - 1) / THREADS, THREADS, 0, stream>>>(degi, dinv, n_nodes);
    k_scan_partial<<<scan_blocks, THREADS, 0, stream>>>(degi, block_sums, n_nodes);
    k_scan_blocks<<<1, THREADS, 0, stream>>>(block_sums, scan_blocks);
    k_scan_final<<<scan_blocks, THREADS, 0, stream>>>(degi, block_sums, offsets, bin_cursor, n_nodes);
    k_bin_scatter<<<(n_edges + 4095) / 4096, 1024, 0, stream>>>(
        src, dst, bin_cursor, edge_binned, n_edges);
    k_csr_scatter<<<nbins, THREADS, 0, stream>>>(
        edge_binned, offsets, edge_src, n_nodes, n_edges);

    const int gemm_blocks = (n_nodes + 63) / 64;
    const int agg_blocks = (n_nodes + (THREADS / 16) - 1) / (THREADS / 16);

    // ---- layer 1 ----
    k_gemm<128><<<gemm_blocks, THREADS, 0, stream>>>(x, W1, dinv, h, n_nodes);
    k_gather_agg<<<agg_blocks, THREADS, 0, stream>>>(
        h, offsets, degi, edge_src, dinv, b1, out, n_nodes);

    // ---- layer 2 ----
    k_gemm<64><<<gemm_blocks, THREADS, 0, stream>>>(out, W2, dinv, h, n_nodes);
    k_gather_agg<<<agg_blocks, THREADS, 0, stream>>>(
        h, offsets, degi, edge_src, dinv, b2, out, n_nodes);
}

// Round 8
// 163.755 us; speedup vs baseline: 4.9013x; 1.0144x over previous
//
#include <hip/hip_runtime.h>
#include <hip/hip_bf16.h>

// ---------------------------------------------------------------------------
// 2-layer GCN (PyG GCNConv semantics) on MI355X.
//   out[d] = relu( dinv[d]*( sum_e H'[src_e] + H'[d] ) + b ),  H' = dinv .* (X@W)
// R1->R2: CSR-gather instead of float atomics.
// R2->R3: device-wide 3-phase scan.
// R3->R4: register-tiled GEMM.
// R4->R5: dinv factored into GEMM epilogue; per-node gather 16 lanes x float4.
// R5->R6: binned LDS-accumulate agg -- REGRESSED (latency-bound).
// R6->R7: two-pass binned scatter (write-amp fix). 166us.
// R7->R8: rocclr fillBuffer for the 200KB degi memset cost 42us (5 GB/s!) --
//         replace with custom grid-strided int4 zero kernel; fold make_dinv
//         into scan_final.
// ---------------------------------------------------------------------------

#define THREADS 256

// --- zero int buffer (replaces hipMemsetAsync / rocclr fillBuffer) ---------
__global__ void k_zero(int4* __restrict__ p, int n4) {
    int i = blockIdx.x * blockDim.x + threadIdx.x;
    if (i < n4) p[i] = make_int4(0, 0, 0, 0);
}

// --- degree count ----------------------------------------------------------
__global__ void k_count_deg(const int* __restrict__ dst, int* __restrict__ degi,
                            int n_edges) {
    int e = blockIdx.x * blockDim.x + threadIdx.x;
    if (e < n_edges) atomicAdd(&degi[dst[e]], 1);
}

// --- 3-phase device-wide exclusive scan ------------------------------------
__global__ void k_scan_partial(const int* __restrict__ degi, int* __restrict__ block_sums,
                               int n_nodes) {
    __shared__ int red[THREADS];
    int i = blockIdx.x * THREADS + threadIdx.x;
    red[threadIdx.x] = (i < n_nodes) ? degi[i] : 0;
    __syncthreads();
    for (int ofs = THREADS >> 1; ofs > 0; ofs >>= 1) {
        if (threadIdx.x < ofs) red[threadIdx.x] += red[threadIdx.x + ofs];
        __syncthreads();
    }
    if (threadIdx.x == 0) block_sums[blockIdx.x] = red[0];
}

__global__ void k_scan_blocks(int* __restrict__ block_sums, int n_blocks) {
    __shared__ int s[THREADS];
    int tid = threadIdx.x;
    s[tid] = (tid < n_blocks) ? block_sums[tid] : 0;
    __syncthreads();
    for (int ofs = 1; ofs < THREADS; ofs <<= 1) {
        int v = (tid >= ofs) ? s[tid - ofs] : 0;
        __syncthreads();
        s[tid] += v;
        __syncthreads();
    }
    if (tid < n_blocks) block_sums[tid] = (tid > 0) ? s[tid - 1] : 0;
}

// offsets[i] = exclusive prefix of degi; dinv[i] = rsqrt(1+degi[i]);
// also init 64-row bin cursors.
__global__ void k_scan_final(const int* __restrict__ degi, const int* __restrict__ block_sums,
                             int* __restrict__ offsets, int* __restrict__ bin_cursor,
                             float* __restrict__ dinv, int n_nodes) {
    __shared__ int s[THREADS];
    int tid = threadIdx.x;
    int i = blockIdx.x * THREADS + tid;
    int v = (i < n_nodes) ? degi[i] : 0;
    s[tid] = v;
    __syncthreads();
    for (int ofs = 1; ofs < THREADS; ofs <<= 1) {
        int t = (tid >= ofs) ? s[tid - ofs] : 0;
        __syncthreads();
        s[tid] += t;
        __syncthreads();
    }
    int excl = s[tid] - v + block_sums[blockIdx.x];
    if (i < n_nodes) {
        offsets[i] = excl;
        dinv[i] = 1.0f / sqrtf((float)(1 + v));
        if ((i & 63) == 0) bin_cursor[i >> 6] = excl;
    }
}

// --- pass 1: bin edges by 64-row dst-bin, coalesced writes -----------------
// 1024 threads x 4 edges = 4096 edges/block. packed = (src<<6) | (dst & 63).
__global__ __launch_bounds__(1024)
void k_bin_scatter(const int* __restrict__ src, const int* __restrict__ dst,
                   int* __restrict__ bin_cursor, unsigned int* __restrict__ edge_binned,
                   int n_edges) {
    __shared__ int cnt[1024];
    __shared__ int lbase[1024];
    __shared__ int gbase[1024];
    __shared__ int run[1024];
    __shared__ unsigned int staged[4096];
    __shared__ unsigned short binarr[4096];
    const int tid = threadIdx.x;
    const int base = blockIdx.x * 4096 + tid * 4;
    cnt[tid] = 0;
    run[tid] = 0;
    __syncthreads();

    int dv[4], sv[4];
    int nv = (base < n_edges) ? min(4, n_edges - base) : 0;
    if (nv == 4) {
        int4 a = *(const int4*)&dst[base];
        dv[0] = a.x; dv[1] = a.y; dv[2] = a.z; dv[3] = a.w;
        int4 b = *(const int4*)&src[base];
        sv[0] = b.x; sv[1] = b.y; sv[2] = b.z; sv[3] = b.w;
    } else {
        for (int j = 0; j < nv; ++j) {
            dv[j] = dst[base + j];
            sv[j] = src[base + j];
        }
    }
    for (int j = 0; j < nv; ++j) atomicAdd(&cnt[dv[j] >> 6], 1);
    __syncthreads();
    int mycnt = cnt[tid];
    for (int ofs = 1; ofs < 1024; ofs <<= 1) {   // inclusive scan in place
        int v = (tid >= ofs) ? cnt[tid - ofs] : 0;
        __syncthreads();
        cnt[tid] += v;
        __syncthreads();
    }
    lbase[tid] = cnt[tid] - mycnt;
    if (mycnt > 0) gbase[tid] = atomicAdd(&bin_cursor[tid], mycnt);
    __syncthreads();
    for (int j = 0; j < nv; ++j) {
        int bn = dv[j] >> 6;
        int rank = atomicAdd(&run[bn], 1);
        int lp = lbase[bn] + rank;
        staged[lp] = ((unsigned)sv[j] << 6) | (unsigned)(dv[j] & 63);
        binarr[lp] = (unsigned short)bn;
    }
    __syncthreads();
    int tot = cnt[1023];
    for (int slot = tid; slot < tot; slot += 1024) {
        int bn = binarr[slot];
        edge_binned[gbase[bn] + (slot - lbase[bn])] = staged[slot];
    }
}

// --- pass 2: binned -> exact CSR (one block per 64-row bin) ----------------
__global__ __launch_bounds__(256)
void k_csr_scatter(const unsigned int* __restrict__ edge_binned,
                   const int* __restrict__ offsets, int* __restrict__ edge_src,
                   int n_nodes, int n_edges) {
    __shared__ int lcur[64];
    const int b = blockIdx.x;
    const int node0 = b << 6;
    const int tid = threadIdx.x;
    if (tid < 64) {
        int node = node0 + tid;
        lcur[tid] = (node < n_nodes) ? offsets[node] : n_edges;
    }
    __syncthreads();
    int ebeg = offsets[node0];
    int node_end = node0 + 64;
    int eend = (node_end < n_nodes) ? offsets[node_end] : n_edges;
    for (int k = ebeg + tid; k < eend; k += 256) {
        unsigned p = edge_binned[k];
        int row = (int)(p & 63u);
        int pos = atomicAdd(&lcur[row], 1);
        edge_src[pos] = (int)(p >> 6);
    }
}

// --- register-tiled GEMM: H'[r,:] = dinv[r] * (X[r,:K] @ W[K,64]) ----------
template <int K>
__global__ __launch_bounds__(256, 2)
void k_gemm(const float* __restrict__ X, const float* __restrict__ W,
            const float* __restrict__ dinv, float* __restrict__ H, int n_rows) {
    constexpr int KQ = K / 4;
    constexpr int RSH = (KQ == 32) ? 5 : 4;
    __shared__ float sW[K * 64];
    __shared__ float sX[64 * K];
    const int tid = threadIdx.x;
    const int row0 = blockIdx.x * 64;

#pragma unroll
    for (int it = 0; it < (K * 64 / 4) / THREADS; ++it) {
        int idx = it * THREADS + tid;
        ((float4*)sW)[idx] = ((const float4*)W)[idx];
    }
#pragma unroll
    for (int it = 0; it < (64 * KQ) / THREADS; ++it) {
        int idx = it * THREADS + tid;
        int kq = idx & (KQ - 1);
        int r = idx >> RSH;
        float4 g = make_float4(0.f, 0.f, 0.f, 0.f);
        int grow = row0 + r;
        if (grow < n_rows) g = *(const float4*)&X[(size_t)grow * K + 4 * kq];
        *(float4*)&sX[r * K + ((kq ^ (r & 7)) << 2)] = g;
    }
    __syncthreads();

    const int tx = tid & 15;
    const int ty = tid >> 4;
    float acc[4][4];
#pragma unroll
    for (int i = 0; i < 4; ++i)
#pragma unroll
        for (int j = 0; j < 4; ++j) acc[i][j] = 0.f;

#pragma unroll 2
    for (int k4 = 0; k4 < KQ; ++k4) {
        float4 b0 = *(const float4*)&sW[(4 * k4 + 0) * 64 + 4 * tx];
        float4 b1 = *(const float4*)&sW[(4 * k4 + 1) * 64 + 4 * tx];
        float4 b2 = *(const float4*)&sW[(4 * k4 + 2) * 64 + 4 * tx];
        float4 b3 = *(const float4*)&sW[(4 * k4 + 3) * 64 + 4 * tx];
#pragma unroll
        for (int i = 0; i < 4; ++i) {
            int r = 4 * ty + i;
            float4 a = *(const float4*)&sX[r * K + ((k4 ^ (r & 7)) << 2)];
            acc[i][0] = fmaf(a.x, b0.x, acc[i][0]);
            acc[i][1] = fmaf(a.x, b0.y, acc[i][1]);
            acc[i][2] = fmaf(a.x, b0.z, acc[i][2]);
            acc[i][3] = fmaf(a.x, b0.w, acc[i][3]);
            acc[i][0] = fmaf(a.y, b1.x, acc[i][0]);
            acc[i][1] = fmaf(a.y, b1.y, acc[i][1]);
            acc[i][2] = fmaf(a.y, b1.z, acc[i][2]);
            acc[i][3] = fmaf(a.y, b1.w, acc[i][3]);
            acc[i][0] = fmaf(a.z, b2.x, acc[i][0]);
            acc[i][1] = fmaf(a.z, b2.y, acc[i][1]);
            acc[i][2] = fmaf(a.z, b2.z, acc[i][2]);
            acc[i][3] = fmaf(a.z, b2.w, acc[i][3]);
            acc[i][0] = fmaf(a.w, b3.x, acc[i][0]);
            acc[i][1] = fmaf(a.w, b3.y, acc[i][1]);
            acc[i][2] = fmaf(a.w, b3.z, acc[i][2]);
            acc[i][3] = fmaf(a.w, b3.w, acc[i][3]);
        }
    }

#pragma unroll
    for (int i = 0; i < 4; ++i) {
        int grow = row0 + 4 * ty + i;
        if (grow < n_rows) {
            float dvv = dinv[grow];
            float4 o = make_float4(acc[i][0] * dvv, acc[i][1] * dvv,
                                   acc[i][2] * dvv, acc[i][3] * dvv);
            *(float4*)&H[(size_t)grow * 64 + 4 * tx] = o;
        }
    }
}

// --- gather-aggregate + fused epilogue -------------------------------------
// 16 lanes x float4 per node, 4 nodes per wave:
//   out[d,:] = relu( dinv[d] * ( sum_e H'[src_e,:] + H'[d,:] ) + b )
__global__ void k_gather_agg(const float* __restrict__ Hp, const int* __restrict__ offsets,
                             const int* __restrict__ degi, const int* __restrict__ edge_src,
                             const float* __restrict__ dinv, const float* __restrict__ b,
                             float* __restrict__ out, int n_nodes) {
    int node = blockIdx.x * (THREADS / 16) + (threadIdx.x >> 4);
    if (node >= n_nodes) return;
    int l = threadIdx.x & 15;            // float4 slot: feats 4l..4l+3
    int start = offsets[node];
    int cnt = degi[node];

    float4 acc = ((const float4*)(Hp + (size_t)node * 64))[l];   // self term

    int k = 0;
    for (; k + 4 <= cnt; k += 4) {
        int s0 = edge_src[start + k];
        int s1 = edge_src[start + k + 1];
        int s2 = edge_src[start + k + 2];
        int s3 = edge_src[start + k + 3];
        float4 v0 = ((const float4*)(Hp + (size_t)s0 * 64))[l];
        float4 v1 = ((const float4*)(Hp + (size_t)s1 * 64))[l];
        float4 v2 = ((const float4*)(Hp + (size_t)s2 * 64))[l];
        float4 v3 = ((const float4*)(Hp + (size_t)s3 * 64))[l];
        acc.x += v0.x + v1.x + v2.x + v3.x;
        acc.y += v0.y + v1.y + v2.y + v3.y;
        acc.z += v0.z + v1.z + v2.z + v3.z;
        acc.w += v0.w + v1.w + v2.w + v3.w;
    }
    for (; k < cnt; ++k) {
        int s0 = edge_src[start + k];
        float4 v0 = ((const float4*)(Hp + (size_t)s0 * 64))[l];
        acc.x += v0.x;
        acc.y += v0.y;
        acc.z += v0.z;
        acc.w += v0.w;
    }

    float dv = dinv[node];
    float4 bb = ((const float4*)b)[l];
    float4 o;
    o.x = fmaxf(fmaf(acc.x, dv, bb.x), 0.0f);
    o.y = fmaxf(fmaf(acc.y, dv, bb.y), 0.0f);
    o.z = fmaxf(fmaf(acc.z, dv, bb.z), 0.0f);
    o.w = fmaxf(fmaf(acc.w, dv, bb.w), 0.0f);
    ((float4*)(out + (size_t)node * 64))[l] = o;
}

extern "C" void kernel_launch(void* const* d_in, const int* in_sizes, int n_in,
                              void* d_out, int out_size, void* d_ws, size_t ws_size,
                              hipStream_t stream) {
    const float* x  = (const float*)d_in[0];
    const int*   ei = (const int*)d_in[1];   // [2, E] int32
    const float* W1 = (const float*)d_in[2];
    const float* b1 = (const float*)d_in[3];
    const float* W2 = (const float*)d_in[4];
    const float* b2 = (const float*)d_in[5];
    float* out = (float*)d_out;

    const int n_feat  = 128;
    const int n_nodes = in_sizes[0] / n_feat;   // 50000
    const int n_edges = in_sizes[1] / 2;        // 800000
    const int* src = ei;
    const int* dst = ei + n_edges;
    const int nbins = (n_nodes + 63) >> 6;      // 782 (<= 1024)
    const int scan_blocks = (n_nodes + THREADS - 1) / THREADS;   // 196 (<= 256)

    // workspace layout (4B units, 16B-aligned chunks)
    const size_t n_pad = (size_t)((n_nodes + 63) & ~63);
    float* dinv        = (float*)d_ws;                   // n_pad
    int*   degi        = (int*)(dinv + n_pad);           // n_pad
    int*   offsets     = degi + n_pad;                   // n_pad
    int*   block_sums  = offsets + n_pad;                // 256
    int*   bin_cursor  = block_sums + 256;               // 1024
    const size_t e_pad = (size_t)((n_edges + 63) & ~63);
    unsigned int* edge_binned = (unsigned int*)(bin_cursor + 1024);  // e_pad
    int*   edge_src    = (int*)(edge_binned + e_pad);    // e_pad
    float* h           = (float*)(edge_src + e_pad);     // n_nodes*64

    // ---- preprocessing (once per call; reused by both layers) ----
    {
        int n4 = (int)(n_pad >> 2);
        k_zero<<<(n4 + THREADS - 1) / THREADS, THREADS, 0, stream>>>((int4*)degi, n4);
    }
    k_count_deg<<<(n_edges + THREADS - 1) / THREADS, THREADS, 0, stream>>>(dst, degi, n_edges);
    k_scan_partial<<<scan_blocks, THREADS, 0, stream>>>(degi, block_sums, n_nodes);
    k_scan_blocks<<<1, THREADS, 0, stream>>>(block_sums, scan_blocks);
    k_scan_final<<<scan_blocks, THREADS, 0, stream>>>(
        degi, block_sums, offsets, bin_cursor, dinv, n_nodes);
    k_bin_scatter<<<(n_edges + 4095) / 4096, 1024, 0, stream>>>(
        src, dst, bin_cursor, edge_binned, n_edges);
    k_csr_scatter<<<nbins, THREADS, 0, stream>>>(
        edge_binned, offsets, edge_src, n_nodes, n_edges);

    const int gemm_blocks = (n_nodes + 63) / 64;
    const int agg_blocks = (n_nodes + (THREADS / 16) - 1) / (THREADS / 16);

    // ---- layer 1 ----
    k_gemm<128><<<gemm_blocks, THREADS, 0, stream>>>(x, W1, dinv, h, n_nodes);
    k_gather_agg<<<agg_blocks, THREADS, 0, stream>>>(
        h, offsets, degi, edge_src, dinv, b1, out, n_nodes);

    // ---- layer 2 ----
    k_gemm<64><<<gemm_blocks, THREADS, 0, stream>>>(out, W2, dinv, h, n_nodes);
    k_gather_agg<<<agg_blocks, THREADS, 0, stream>>>(
        h, offsets, degi, edge_src, dinv, b2, out, n_nodes);
}

// Round 9
// 145.298 us; speedup vs baseline: 5.5239x; 1.1270x over previous
//
#include <hip/hip_runtime.h>
#include <hip/hip_bf16.h>

// ---------------------------------------------------------------------------
// 2-layer GCN (PyG GCNConv semantics) on MI355X.
//   out[d] = relu( dinv[d]*( sum_e H'[src_e] + H'[d] ) + b ),  H' = dinv .* (X@W)
// R1->R2: CSR-gather instead of float atomics.
// R2->R3: device-wide 3-phase scan.
// R3->R4: register-tiled GEMM.
// R4->R5: dinv factored into GEMM epilogue; per-node gather 16 lanes x float4.
// R5->R6: binned LDS-accumulate agg -- REGRESSED (latency-bound).
// R6->R7: two-pass binned scatter (write-amp fix). 166us.
// R7->R8: custom zero kernel instead of rocclr fill. 164us.
// R8->R9: fuse per-node degree/offset/CSR work into the bin pass:
//   k_bin_count: 782-bin LDS histogram (kills 800K-atomic count_deg),
//   k_bin_scan: single-block scan over bins (kills 50K 3-phase scan),
//   k_csr_build: per-bin LDS degree count + scan + exact-CSR scatter +
//                offsets/degi/dinv emit (kills k_csr_scatter).
//   Gather unrolled 8-deep.
// ---------------------------------------------------------------------------

#define THREADS 256

// --- tiny zero (bincnt only, 1024 ints) ------------------------------------
__global__ void k_zero(int4* __restrict__ p, int n4) {
    int i = blockIdx.x * blockDim.x + threadIdx.x;
    if (i < n4) p[i] = make_int4(0, 0, 0, 0);
}

// --- per-bin histogram of dst (64-row bins), LDS-aggregated ----------------
// 256 threads x 16 edges = 4096 edges/block.
__global__ __launch_bounds__(256)
void k_bin_count(const int* __restrict__ dst, int* __restrict__ bincnt,
                 int n_edges) {
    __shared__ int hist[1024];
    const int tid = threadIdx.x;
    for (int i = tid; i < 1024; i += 256) hist[i] = 0;
    __syncthreads();
    const int base = blockIdx.x * 4096 + tid * 16;
#pragma unroll
    for (int j = 0; j < 4; ++j) {
        int o = base + j * 4;
        if (o + 4 <= n_edges) {
            int4 d = *(const int4*)&dst[o];
            atomicAdd(&hist[d.x >> 6], 1);
            atomicAdd(&hist[d.y >> 6], 1);
            atomicAdd(&hist[d.z >> 6], 1);
            atomicAdd(&hist[d.w >> 6], 1);
        } else {
            for (int t = o; t < n_edges; ++t) atomicAdd(&hist[dst[t] >> 6], 1);
        }
    }
    __syncthreads();
    for (int i = tid; i < 1024; i += 256)
        if (hist[i]) atomicAdd(&bincnt[i], hist[i]);
}

// --- single-block scan over bins -> bin_base (exclusive), cursor, sentinel -
__global__ __launch_bounds__(1024)
void k_bin_scan(const int* __restrict__ bincnt, int* __restrict__ bin_base,
                int* __restrict__ bin_cursor, int nbins) {
    __shared__ int s[1024];
    const int tid = threadIdx.x;
    int v = (tid < nbins) ? bincnt[tid] : 0;
    s[tid] = v;
    __syncthreads();
    for (int ofs = 1; ofs < 1024; ofs <<= 1) {
        int t = (tid >= ofs) ? s[tid - ofs] : 0;
        __syncthreads();
        s[tid] += t;
        __syncthreads();
    }
    if (tid < nbins) {
        int excl = s[tid] - v;
        bin_base[tid] = excl;
        bin_cursor[tid] = excl;
    }
    if (tid == 0) bin_base[nbins] = s[1023];
}

// --- pass 1: bin edges by 64-row dst-bin, coalesced writes -----------------
// 1024 threads x 4 edges = 4096 edges/block. packed = (src<<6) | (dst & 63).
__global__ __launch_bounds__(1024)
void k_bin_scatter(const int* __restrict__ src, const int* __restrict__ dst,
                   int* __restrict__ bin_cursor, unsigned int* __restrict__ edge_binned,
                   int n_edges) {
    __shared__ int cnt[1024];
    __shared__ int lbase[1024];
    __shared__ int gbase[1024];
    __shared__ int run[1024];
    __shared__ unsigned int staged[4096];
    __shared__ unsigned short binarr[4096];
    const int tid = threadIdx.x;
    const int base = blockIdx.x * 4096 + tid * 4;
    cnt[tid] = 0;
    run[tid] = 0;
    __syncthreads();

    int dv[4], sv[4];
    int nv = (base < n_edges) ? min(4, n_edges - base) : 0;
    if (nv == 4) {
        int4 a = *(const int4*)&dst[base];
        dv[0] = a.x; dv[1] = a.y; dv[2] = a.z; dv[3] = a.w;
        int4 b = *(const int4*)&src[base];
        sv[0] = b.x; sv[1] = b.y; sv[2] = b.z; sv[3] = b.w;
    } else {
        for (int j = 0; j < nv; ++j) {
            dv[j] = dst[base + j];
            sv[j] = src[base + j];
        }
    }
    for (int j = 0; j < nv; ++j) atomicAdd(&cnt[dv[j] >> 6], 1);
    __syncthreads();
    int mycnt = cnt[tid];
    for (int ofs = 1; ofs < 1024; ofs <<= 1) {   // inclusive scan in place
        int v = (tid >= ofs) ? cnt[tid - ofs] : 0;
        __syncthreads();
        cnt[tid] += v;
        __syncthreads();
    }
    lbase[tid] = cnt[tid] - mycnt;
    if (mycnt > 0) gbase[tid] = atomicAdd(&bin_cursor[tid], mycnt);
    __syncthreads();
    for (int j = 0; j < nv; ++j) {
        int bn = dv[j] >> 6;
        int rank = atomicAdd(&run[bn], 1);
        int lp = lbase[bn] + rank;
        staged[lp] = ((unsigned)sv[j] << 6) | (unsigned)(dv[j] & 63);
        binarr[lp] = (unsigned short)bn;
    }
    __syncthreads();
    int tot = cnt[1023];
    for (int slot = tid; slot < tot; slot += 1024) {
        int bn = binarr[slot];
        edge_binned[gbase[bn] + (slot - lbase[bn])] = staged[slot];
    }
}

// --- pass 2: per-bin degree count + scan + exact CSR + node metadata -------
// one block per 64-row bin. Emits offsets/degi/dinv AND exact-CSR edge_src.
__global__ __launch_bounds__(256)
void k_csr_build(const unsigned int* __restrict__ edge_binned,
                 const int* __restrict__ bin_base, int* __restrict__ edge_src,
                 int* __restrict__ offsets, int* __restrict__ degi,
                 float* __restrict__ dinv, int n_nodes) {
    __shared__ int lcnt[64];
    __shared__ int sc[64];
    __shared__ int lcur[64];
    const int b = blockIdx.x;
    const int node0 = b << 6;
    const int tid = threadIdx.x;
    const int ebeg = bin_base[b];
    const int eend = bin_base[b + 1];

    if (tid < 64) lcnt[tid] = 0;
    __syncthreads();
    for (int k = ebeg + tid; k < eend; k += 256)
        atomicAdd(&lcnt[edge_binned[k] & 63u], 1);
    __syncthreads();

    // inclusive scan of 64 counts (first 64 threads; block barriers)
    if (tid < 64) sc[tid] = lcnt[tid];
    __syncthreads();
    for (int ofs = 1; ofs < 64; ofs <<= 1) {
        int v = 0;
        if (tid < 64 && tid >= ofs) v = sc[tid - ofs];
        __syncthreads();
        if (tid < 64) sc[tid] += v;
        __syncthreads();
    }
    if (tid < 64) {
        int cntv = lcnt[tid];
        int excl = ebeg + sc[tid] - cntv;
        lcur[tid] = excl;
        int node = node0 + tid;
        if (node < n_nodes) {
            offsets[node] = excl;
            degi[node] = cntv;
            dinv[node] = 1.0f / sqrtf((float)(1 + cntv));
        }
    }
    __syncthreads();
    for (int k = ebeg + tid; k < eend; k += 256) {
        unsigned p = edge_binned[k];
        int pos = atomicAdd(&lcur[p & 63u], 1);
        edge_src[pos] = (int)(p >> 6);
    }
}

// --- register-tiled GEMM: H'[r,:] = dinv[r] * (X[r,:K] @ W[K,64]) ----------
template <int K>
__global__ __launch_bounds__(256, 2)
void k_gemm(const float* __restrict__ X, const float* __restrict__ W,
            const float* __restrict__ dinv, float* __restrict__ H, int n_rows) {
    constexpr int KQ = K / 4;
    constexpr int RSH = (KQ == 32) ? 5 : 4;
    __shared__ float sW[K * 64];
    __shared__ float sX[64 * K];
    const int tid = threadIdx.x;
    const int row0 = blockIdx.x * 64;

#pragma unroll
    for (int it = 0; it < (K * 64 / 4) / THREADS; ++it) {
        int idx = it * THREADS + tid;
        ((float4*)sW)[idx] = ((const float4*)W)[idx];
    }
#pragma unroll
    for (int it = 0; it < (64 * KQ) / THREADS; ++it) {
        int idx = it * THREADS + tid;
        int kq = idx & (KQ - 1);
        int r = idx >> RSH;
        float4 g = make_float4(0.f, 0.f, 0.f, 0.f);
        int grow = row0 + r;
        if (grow < n_rows) g = *(const float4*)&X[(size_t)grow * K + 4 * kq];
        *(float4*)&sX[r * K + ((kq ^ (r & 7)) << 2)] = g;
    }
    __syncthreads();

    const int tx = tid & 15;
    const int ty = tid >> 4;
    float acc[4][4];
#pragma unroll
    for (int i = 0; i < 4; ++i)
#pragma unroll
        for (int j = 0; j < 4; ++j) acc[i][j] = 0.f;

#pragma unroll 2
    for (int k4 = 0; k4 < KQ; ++k4) {
        float4 b0 = *(const float4*)&sW[(4 * k4 + 0) * 64 + 4 * tx];
        float4 b1 = *(const float4*)&sW[(4 * k4 + 1) * 64 + 4 * tx];
        float4 b2 = *(const float4*)&sW[(4 * k4 + 2) * 64 + 4 * tx];
        float4 b3 = *(const float4*)&sW[(4 * k4 + 3) * 64 + 4 * tx];
#pragma unroll
        for (int i = 0; i < 4; ++i) {
            int r = 4 * ty + i;
            float4 a = *(const float4*)&sX[r * K + ((k4 ^ (r & 7)) << 2)];
            acc[i][0] = fmaf(a.x, b0.x, acc[i][0]);
            acc[i][1] = fmaf(a.x, b0.y, acc[i][1]);
            acc[i][2] = fmaf(a.x, b0.z, acc[i][2]);
            acc[i][3] = fmaf(a.x, b0.w, acc[i][3]);
            acc[i][0] = fmaf(a.y, b1.x, acc[i][0]);
            acc[i][1] = fmaf(a.y, b1.y, acc[i][1]);
            acc[i][2] = fmaf(a.y, b1.z, acc[i][2]);
            acc[i][3] = fmaf(a.y, b1.w, acc[i][3]);
            acc[i][0] = fmaf(a.z, b2.x, acc[i][0]);
            acc[i][1] = fmaf(a.z, b2.y, acc[i][1]);
            acc[i][2] = fmaf(a.z, b2.z, acc[i][2]);
            acc[i][3] = fmaf(a.z, b2.w, acc[i][3]);
            acc[i][0] = fmaf(a.w, b3.x, acc[i][0]);
            acc[i][1] = fmaf(a.w, b3.y, acc[i][1]);
            acc[i][2] = fmaf(a.w, b3.z, acc[i][2]);
            acc[i][3] = fmaf(a.w, b3.w, acc[i][3]);
        }
    }

#pragma unroll
    for (int i = 0; i < 4; ++i) {
        int grow = row0 + 4 * ty + i;
        if (grow < n_rows) {
            float dvv = dinv[grow];
            float4 o = make_float4(acc[i][0] * dvv, acc[i][1] * dvv,
                                   acc[i][2] * dvv, acc[i][3] * dvv);
            *(float4*)&H[(size_t)grow * 64 + 4 * tx] = o;
        }
    }
}

// --- gather-aggregate + fused epilogue -------------------------------------
// 16 lanes x float4 per node, 4 nodes per wave; 8-deep unroll for MLP:
//   out[d,:] = relu( dinv[d] * ( sum_e H'[src_e,:] + H'[d,:] ) + b )
__global__ void k_gather_agg(const float* __restrict__ Hp, const int* __restrict__ offsets,
                             const int* __restrict__ degi, const int* __restrict__ edge_src,
                             const float* __restrict__ dinv, const float* __restrict__ b,
                             float* __restrict__ out, int n_nodes) {
    int node = blockIdx.x * (THREADS / 16) + (threadIdx.x >> 4);
    if (node >= n_nodes) return;
    int l = threadIdx.x & 15;            // float4 slot: feats 4l..4l+3
    int start = offsets[node];
    int cnt = degi[node];

    float4 acc = ((const float4*)(Hp + (size_t)node * 64))[l];   // self term

    int k = 0;
    for (; k + 8 <= cnt; k += 8) {
        int s0 = edge_src[start + k];
        int s1 = edge_src[start + k + 1];
        int s2 = edge_src[start + k + 2];
        int s3 = edge_src[start + k + 3];
        int s4 = edge_src[start + k + 4];
        int s5 = edge_src[start + k + 5];
        int s6 = edge_src[start + k + 6];
        int s7 = edge_src[start + k + 7];
        float4 v0 = ((const float4*)(Hp + (size_t)s0 * 64))[l];
        float4 v1 = ((const float4*)(Hp + (size_t)s1 * 64))[l];
        float4 v2 = ((const float4*)(Hp + (size_t)s2 * 64))[l];
        float4 v3 = ((const float4*)(Hp + (size_t)s3 * 64))[l];
        float4 v4 = ((const float4*)(Hp + (size_t)s4 * 64))[l];
        float4 v5 = ((const float4*)(Hp + (size_t)s5 * 64))[l];
        float4 v6 = ((const float4*)(Hp + (size_t)s6 * 64))[l];
        float4 v7 = ((const float4*)(Hp + (size_t)s7 * 64))[l];
        acc.x += (v0.x + v1.x) + (v2.x + v3.x) + ((v4.x + v5.x) + (v6.x + v7.x));
        acc.y += (v0.y + v1.y) + (v2.y + v3.y) + ((v4.y + v5.y) + (v6.y + v7.y));
        acc.z += (v0.z + v1.z) + (v2.z + v3.z) + ((v4.z + v5.z) + (v6.z + v7.z));
        acc.w += (v0.w + v1.w) + (v2.w + v3.w) + ((v4.w + v5.w) + (v6.w + v7.w));
    }
    for (; k + 4 <= cnt; k += 4) {
        int s0 = edge_src[start + k];
        int s1 = edge_src[start + k + 1];
        int s2 = edge_src[start + k + 2];
        int s3 = edge_src[start + k + 3];
        float4 v0 = ((const float4*)(Hp + (size_t)s0 * 64))[l];
        float4 v1 = ((const float4*)(Hp + (size_t)s1 * 64))[l];
        float4 v2 = ((const float4*)(Hp + (size_t)s2 * 64))[l];
        float4 v3 = ((const float4*)(Hp + (size_t)s3 * 64))[l];
        acc.x += (v0.x + v1.x) + (v2.x + v3.x);
        acc.y += (v0.y + v1.y) + (v2.y + v3.y);
        acc.z += (v0.z + v1.z) + (v2.z + v3.z);
        acc.w += (v0.w + v1.w) + (v2.w + v3.w);
    }
    for (; k < cnt; ++k) {
        int s0 = edge_src[start + k];
        float4 v0 = ((const float4*)(Hp + (size_t)s0 * 64))[l];
        acc.x += v0.x;
        acc.y += v0.y;
        acc.z += v0.z;
        acc.w += v0.w;
    }

    float dv = dinv[node];
    float4 bb = ((const float4*)b)[l];
    float4 o;
    o.x = fmaxf(fmaf(acc.x, dv, bb.x), 0.0f);
    o.y = fmaxf(fmaf(acc.y, dv, bb.y), 0.0f);
    o.z = fmaxf(fmaf(acc.z, dv, bb.z), 0.0f);
    o.w = fmaxf(fmaf(acc.w, dv, bb.w), 0.0f);
    ((float4*)(out + (size_t)node * 64))[l] = o;
}

extern "C" void kernel_launch(void* const* d_in, const int* in_sizes, int n_in,
                              void* d_out, int out_size, void* d_ws, size_t ws_size,
                              hipStream_t stream) {
    const float* x  = (const float*)d_in[0];
    const int*   ei = (const int*)d_in[1];   // [2, E] int32
    const float* W1 = (const float*)d_in[2];
    const float* b1 = (const float*)d_in[3];
    const float* W2 = (const float*)d_in[4];
    const float* b2 = (const float*)d_in[5];
    float* out = (float*)d_out;

    const int n_feat  = 128;
    const int n_nodes = in_sizes[0] / n_feat;   // 50000
    const int n_edges = in_sizes[1] / 2;        // 800000
    const int* src = ei;
    const int* dst = ei + n_edges;
    const int nbins = (n_nodes + 63) >> 6;      // 782 (<= 1023)

    // workspace layout (4B units, 16B-aligned chunks)
    const size_t n_pad = (size_t)((n_nodes + 63) & ~63);
    float* dinv        = (float*)d_ws;                   // n_pad
    int*   degi        = (int*)(dinv + n_pad);           // n_pad
    int*   offsets     = degi + n_pad;                   // n_pad
    int*   bincnt      = offsets + n_pad;                // 1024
    int*   bin_base    = bincnt + 1024;                  // 1024 + sentinel
    int*   bin_cursor  = bin_base + 1040;                // 1024
    const size_t e_pad = (size_t)((n_edges + 63) & ~63);
    unsigned int* edge_binned = (unsigned int*)(bin_cursor + 1024);  // e_pad
    int*   edge_src    = (int*)(edge_binned + e_pad);    // e_pad
    float* h           = (float*)(edge_src + e_pad);     // n_nodes*64

    // ---- preprocessing (once per call; reused by both layers) ----
    k_zero<<<1, THREADS, 0, stream>>>((int4*)bincnt, 256);
    k_bin_count<<<(n_edges + 4095) / 4096, THREADS, 0, stream>>>(dst, bincnt, n_edges);
    k_bin_scan<<<1, 1024, 0, stream>>>(bincnt, bin_base, bin_cursor, nbins);
    k_bin_scatter<<<(n_edges + 4095) / 4096, 1024, 0, stream>>>(
        src, dst, bin_cursor, edge_binned, n_edges);
    k_csr_build<<<nbins, THREADS, 0, stream>>>(
        edge_binned, bin_base, edge_src, offsets, degi, dinv, n_nodes);

    const int gemm_blocks = (n_nodes + 63) / 64;
    const int agg_blocks = (n_nodes + (THREADS / 16) - 1) / (THREADS / 16);

    // ---- layer 1 ----
    k_gemm<128><<<gemm_blocks, THREADS, 0, stream>>>(x, W1, dinv, h, n_nodes);
    k_gather_agg<<<agg_blocks, THREADS, 0, stream>>>(
        h, offsets, degi, edge_src, dinv, b1, out, n_nodes);

    // ---- layer 2 ----
    k_gemm<64><<<gemm_blocks, THREADS, 0, stream>>>(out, W2, dinv, h, n_nodes);
    k_gather_agg<<<agg_blocks, THREADS, 0, stream>>>(
        h, offsets, degi, edge_src, dinv, b2, out, n_nodes);
}

// Round 10
// 116.630 us; speedup vs baseline: 6.8817x; 1.2458x over previous
//
#include <hip/hip_runtime.h>
#include <hip/hip_bf16.h>
#include <hip/hip_fp16.h>

// ---------------------------------------------------------------------------
// 2-layer GCN (PyG GCNConv semantics) on MI355X.
//   out[d] = relu( dinv[d]*( sum_e H'[src_e] + H'[d] ) + b ),  H' = dinv .* (X@W)
// R1->R2: CSR-gather instead of float atomics.
// R2->R3: device-wide 3-phase scan.
// R3->R4: register-tiled GEMM.
// R4->R5: dinv factored into GEMM epilogue; per-node gather.
// R5->R6: binned LDS-accumulate agg -- REGRESSED (latency-bound).
// R6->R7: two-pass binned scatter (write-amp fix). 166us.
// R7->R8: custom zero kernel. 164us.
// R8->R9: preprocess fused into bin pipeline (bin hist + bin scan +
//         bin scatter + per-bin CSR build). 145us.
// R9->R10: H' stored fp16 (pure intermediate; halves gather fetch + GEMM
//          write). Gather reshaped: 8 lanes x half8/node, 8 nodes/wave,
//          8-deep unroll; fp32 accumulation; out stays fp32.
// ---------------------------------------------------------------------------

#define THREADS 256

// --- tiny zero (bincnt only, 1024 ints) ------------------------------------
__global__ void k_zero(int4* __restrict__ p, int n4) {
    int i = blockIdx.x * blockDim.x + threadIdx.x;
    if (i < n4) p[i] = make_int4(0, 0, 0, 0);
}

// --- per-bin histogram of dst (64-row bins), LDS-aggregated ----------------
// 256 threads x 16 edges = 4096 edges/block.
__global__ __launch_bounds__(256)
void k_bin_count(const int* __restrict__ dst, int* __restrict__ bincnt,
                 int n_edges) {
    __shared__ int hist[1024];
    const int tid = threadIdx.x;
    for (int i = tid; i < 1024; i += 256) hist[i] = 0;
    __syncthreads();
    const int base = blockIdx.x * 4096 + tid * 16;
#pragma unroll
    for (int j = 0; j < 4; ++j) {
        int o = base + j * 4;
        if (o + 4 <= n_edges) {
            int4 d = *(const int4*)&dst[o];
            atomicAdd(&hist[d.x >> 6], 1);
            atomicAdd(&hist[d.y >> 6], 1);
            atomicAdd(&hist[d.z >> 6], 1);
            atomicAdd(&hist[d.w >> 6], 1);
        } else {
            for (int t = o; t < n_edges; ++t) atomicAdd(&hist[dst[t] >> 6], 1);
        }
    }
    __syncthreads();
    for (int i = tid; i < 1024; i += 256)
        if (hist[i]) atomicAdd(&bincnt[i], hist[i]);
}

// --- single-block scan over bins -> bin_base (exclusive), cursor, sentinel -
__global__ __launch_bounds__(1024)
void k_bin_scan(const int* __restrict__ bincnt, int* __restrict__ bin_base,
                int* __restrict__ bin_cursor, int nbins) {
    __shared__ int s[1024];
    const int tid = threadIdx.x;
    int v = (tid < nbins) ? bincnt[tid] : 0;
    s[tid] = v;
    __syncthreads();
    for (int ofs = 1; ofs < 1024; ofs <<= 1) {
        int t = (tid >= ofs) ? s[tid - ofs] : 0;
        __syncthreads();
        s[tid] += t;
        __syncthreads();
    }
    if (tid < nbins) {
        int excl = s[tid] - v;
        bin_base[tid] = excl;
        bin_cursor[tid] = excl;
    }
    if (tid == 0) bin_base[nbins] = s[1023];
}

// --- pass 1: bin edges by 64-row dst-bin, coalesced writes -----------------
// 1024 threads x 4 edges = 4096 edges/block. packed = (src<<6) | (dst & 63).
__global__ __launch_bounds__(1024)
void k_bin_scatter(const int* __restrict__ src, const int* __restrict__ dst,
                   int* __restrict__ bin_cursor, unsigned int* __restrict__ edge_binned,
                   int n_edges) {
    __shared__ int cnt[1024];
    __shared__ int lbase[1024];
    __shared__ int gbase[1024];
    __shared__ int run[1024];
    __shared__ unsigned int staged[4096];
    __shared__ unsigned short binarr[4096];
    const int tid = threadIdx.x;
    const int base = blockIdx.x * 4096 + tid * 4;
    cnt[tid] = 0;
    run[tid] = 0;
    __syncthreads();

    int dv[4], sv[4];
    int nv = (base < n_edges) ? min(4, n_edges - base) : 0;
    if (nv == 4) {
        int4 a = *(const int4*)&dst[base];
        dv[0] = a.x; dv[1] = a.y; dv[2] = a.z; dv[3] = a.w;
        int4 b = *(const int4*)&src[base];
        sv[0] = b.x; sv[1] = b.y; sv[2] = b.z; sv[3] = b.w;
    } else {
        for (int j = 0; j < nv; ++j) {
            dv[j] = dst[base + j];
            sv[j] = src[base + j];
        }
    }
    for (int j = 0; j < nv; ++j) atomicAdd(&cnt[dv[j] >> 6], 1);
    __syncthreads();
    int mycnt = cnt[tid];
    for (int ofs = 1; ofs < 1024; ofs <<= 1) {   // inclusive scan in place
        int v = (tid >= ofs) ? cnt[tid - ofs] : 0;
        __syncthreads();
        cnt[tid] += v;
        __syncthreads();
    }
    lbase[tid] = cnt[tid] - mycnt;
    if (mycnt > 0) gbase[tid] = atomicAdd(&bin_cursor[tid], mycnt);
    __syncthreads();
    for (int j = 0; j < nv; ++j) {
        int bn = dv[j] >> 6;
        int rank = atomicAdd(&run[bn], 1);
        int lp = lbase[bn] + rank;
        staged[lp] = ((unsigned)sv[j] << 6) | (unsigned)(dv[j] & 63);
        binarr[lp] = (unsigned short)bn;
    }
    __syncthreads();
    int tot = cnt[1023];
    for (int slot = tid; slot < tot; slot += 1024) {
        int bn = binarr[slot];
        edge_binned[gbase[bn] + (slot - lbase[bn])] = staged[slot];
    }
}

// --- pass 2: per-bin degree count + scan + exact CSR + node metadata -------
// one block per 64-row bin. Emits offsets/degi/dinv AND exact-CSR edge_src.
__global__ __launch_bounds__(256)
void k_csr_build(const unsigned int* __restrict__ edge_binned,
                 const int* __restrict__ bin_base, int* __restrict__ edge_src,
                 int* __restrict__ offsets, int* __restrict__ degi,
                 float* __restrict__ dinv, int n_nodes) {
    __shared__ int lcnt[64];
    __shared__ int sc[64];
    __shared__ int lcur[64];
    const int b = blockIdx.x;
    const int node0 = b << 6;
    const int tid = threadIdx.x;
    const int ebeg = bin_base[b];
    const int eend = bin_base[b + 1];

    if (tid < 64) lcnt[tid] = 0;
    __syncthreads();
    for (int k = ebeg + tid; k < eend; k += 256)
        atomicAdd(&lcnt[edge_binned[k] & 63u], 1);
    __syncthreads();

    if (tid < 64) sc[tid] = lcnt[tid];
    __syncthreads();
    for (int ofs = 1; ofs < 64; ofs <<= 1) {
        int v = 0;
        if (tid < 64 && tid >= ofs) v = sc[tid - ofs];
        __syncthreads();
        if (tid < 64) sc[tid] += v;
        __syncthreads();
    }
    if (tid < 64) {
        int cntv = lcnt[tid];
        int excl = ebeg + sc[tid] - cntv;
        lcur[tid] = excl;
        int node = node0 + tid;
        if (node < n_nodes) {
            offsets[node] = excl;
            degi[node] = cntv;
            dinv[node] = 1.0f / sqrtf((float)(1 + cntv));
        }
    }
    __syncthreads();
    for (int k = ebeg + tid; k < eend; k += 256) {
        unsigned p = edge_binned[k];
        int pos = atomicAdd(&lcur[p & 63u], 1);
        edge_src[pos] = (int)(p >> 6);
    }
}

// --- register-tiled GEMM: H'[r,:] = fp16( dinv[r] * (X[r,:K] @ W[K,64]) ) --
template <int K>
__global__ __launch_bounds__(256, 2)
void k_gemm(const float* __restrict__ X, const float* __restrict__ W,
            const float* __restrict__ dinv, __half* __restrict__ H, int n_rows) {
    constexpr int KQ = K / 4;
    constexpr int RSH = (KQ == 32) ? 5 : 4;
    __shared__ float sW[K * 64];
    __shared__ float sX[64 * K];
    const int tid = threadIdx.x;
    const int row0 = blockIdx.x * 64;

#pragma unroll
    for (int it = 0; it < (K * 64 / 4) / THREADS; ++it) {
        int idx = it * THREADS + tid;
        ((float4*)sW)[idx] = ((const float4*)W)[idx];
    }
#pragma unroll
    for (int it = 0; it < (64 * KQ) / THREADS; ++it) {
        int idx = it * THREADS + tid;
        int kq = idx & (KQ - 1);
        int r = idx >> RSH;
        float4 g = make_float4(0.f, 0.f, 0.f, 0.f);
        int grow = row0 + r;
        if (grow < n_rows) g = *(const float4*)&X[(size_t)grow * K + 4 * kq];
        *(float4*)&sX[r * K + ((kq ^ (r & 7)) << 2)] = g;
    }
    __syncthreads();

    const int tx = tid & 15;
    const int ty = tid >> 4;
    float acc[4][4];
#pragma unroll
    for (int i = 0; i < 4; ++i)
#pragma unroll
        for (int j = 0; j < 4; ++j) acc[i][j] = 0.f;

#pragma unroll 2
    for (int k4 = 0; k4 < KQ; ++k4) {
        float4 b0 = *(const float4*)&sW[(4 * k4 + 0) * 64 + 4 * tx];
        float4 b1 = *(const float4*)&sW[(4 * k4 + 1) * 64 + 4 * tx];
        float4 b2 = *(const float4*)&sW[(4 * k4 + 2) * 64 + 4 * tx];
        float4 b3 = *(const float4*)&sW[(4 * k4 + 3) * 64 + 4 * tx];
#pragma unroll
        for (int i = 0; i < 4; ++i) {
            int r = 4 * ty + i;
            float4 a = *(const float4*)&sX[r * K + ((k4 ^ (r & 7)) << 2)];
            acc[i][0] = fmaf(a.x, b0.x, acc[i][0]);
            acc[i][1] = fmaf(a.x, b0.y, acc[i][1]);
            acc[i][2] = fmaf(a.x, b0.z, acc[i][2]);
            acc[i][3] = fmaf(a.x, b0.w, acc[i][3]);
            acc[i][0] = fmaf(a.y, b1.x, acc[i][0]);
            acc[i][1] = fmaf(a.y, b1.y, acc[i][1]);
            acc[i][2] = fmaf(a.y, b1.z, acc[i][2]);
            acc[i][3] = fmaf(a.y, b1.w, acc[i][3]);
            acc[i][0] = fmaf(a.z, b2.x, acc[i][0]);
            acc[i][1] = fmaf(a.z, b2.y, acc[i][1]);
            acc[i][2] = fmaf(a.z, b2.z, acc[i][2]);
            acc[i][3] = fmaf(a.z, b2.w, acc[i][3]);
            acc[i][0] = fmaf(a.w, b3.x, acc[i][0]);
            acc[i][1] = fmaf(a.w, b3.y, acc[i][1]);
            acc[i][2] = fmaf(a.w, b3.z, acc[i][2]);
            acc[i][3] = fmaf(a.w, b3.w, acc[i][3]);
        }
    }

#pragma unroll
    for (int i = 0; i < 4; ++i) {
        int grow = row0 + 4 * ty + i;
        if (grow < n_rows) {
            float dvv = dinv[grow];
            union { __half2 h[2]; uint2 u; } pk;
            pk.h[0] = __floats2half2_rn(acc[i][0] * dvv, acc[i][1] * dvv);
            pk.h[1] = __floats2half2_rn(acc[i][2] * dvv, acc[i][3] * dvv);
            *(uint2*)&H[(size_t)grow * 64 + 4 * tx] = pk.u;
        }
    }
}

// --- gather-aggregate + fused epilogue (fp16 rows, fp32 accum) -------------
// 8 lanes x half8 (16B) per node, 8 nodes per wave, 8-deep unroll:
//   out[d,:] = relu( dinv[d] * ( sum_e H'[src_e,:] + H'[d,:] ) + b )
__device__ inline void acc_row16(float2 acc[4], uint4 u) {
    const __half2* hp = (const __half2*)&u;
    float2 a = __half22float2(hp[0]);
    float2 b = __half22float2(hp[1]);
    float2 c = __half22float2(hp[2]);
    float2 d = __half22float2(hp[3]);
    acc[0].x += a.x; acc[0].y += a.y;
    acc[1].x += b.x; acc[1].y += b.y;
    acc[2].x += c.x; acc[2].y += c.y;
    acc[3].x += d.x; acc[3].y += d.y;
}

__global__ void k_gather_agg(const __half* __restrict__ Hp, const int* __restrict__ offsets,
                             const int* __restrict__ degi, const int* __restrict__ edge_src,
                             const float* __restrict__ dinv, const float* __restrict__ b,
                             float* __restrict__ out, int n_nodes) {
    int node = blockIdx.x * (THREADS / 8) + (threadIdx.x >> 3);
    if (node >= n_nodes) return;
    int l = threadIdx.x & 7;             // half8 slot: feats 8l..8l+7
    int start = offsets[node];
    int cnt = degi[node];

    float2 acc[4];
    acc_row16(acc, *(const uint4*)(Hp + ((size_t)node << 6) + (l << 3)));  // init via self term
    // acc currently = self + garbage? No: acc uninitialized -> set from self:
    // (acc_row16 adds; so initialize first)
    // -- handled below by re-ordering: initialize then add. See code:
    // NOTE: acc was uninitialized above; fix by zero-init then add self.
    // (kept simple: restart)
    acc[0] = make_float2(0.f, 0.f); acc[1] = make_float2(0.f, 0.f);
    acc[2] = make_float2(0.f, 0.f); acc[3] = make_float2(0.f, 0.f);
    acc_row16(acc, *(const uint4*)(Hp + ((size_t)node << 6) + (l << 3)));

    int k = 0;
    for (; k + 8 <= cnt; k += 8) {
        int s0 = edge_src[start + k];
        int s1 = edge_src[start + k + 1];
        int s2 = edge_src[start + k + 2];
        int s3 = edge_src[start + k + 3];
        int s4 = edge_src[start + k + 4];
        int s5 = edge_src[start + k + 5];
        int s6 = edge_src[start + k + 6];
        int s7 = edge_src[start + k + 7];
        uint4 u0 = *(const uint4*)(Hp + ((size_t)s0 << 6) + (l << 3));
        uint4 u1 = *(const uint4*)(Hp + ((size_t)s1 << 6) + (l << 3));
        uint4 u2 = *(const uint4*)(Hp + ((size_t)s2 << 6) + (l << 3));
        uint4 u3 = *(const uint4*)(Hp + ((size_t)s3 << 6) + (l << 3));
        uint4 u4 = *(const uint4*)(Hp + ((size_t)s4 << 6) + (l << 3));
        uint4 u5 = *(const uint4*)(Hp + ((size_t)s5 << 6) + (l << 3));
        uint4 u6 = *(const uint4*)(Hp + ((size_t)s6 << 6) + (l << 3));
        uint4 u7 = *(const uint4*)(Hp + ((size_t)s7 << 6) + (l << 3));
        acc_row16(acc, u0);
        acc_row16(acc, u1);
        acc_row16(acc, u2);
        acc_row16(acc, u3);
        acc_row16(acc, u4);
        acc_row16(acc, u5);
        acc_row16(acc, u6);
        acc_row16(acc, u7);
    }
    for (; k + 4 <= cnt; k += 4) {
        int s0 = edge_src[start + k];
        int s1 = edge_src[start + k + 1];
        int s2 = edge_src[start + k + 2];
        int s3 = edge_src[start + k + 3];
        uint4 u0 = *(const uint4*)(Hp + ((size_t)s0 << 6) + (l << 3));
        uint4 u1 = *(const uint4*)(Hp + ((size_t)s1 << 6) + (l << 3));
        uint4 u2 = *(const uint4*)(Hp + ((size_t)s2 << 6) + (l << 3));
        uint4 u3 = *(const uint4*)(Hp + ((size_t)s3 << 6) + (l << 3));
        acc_row16(acc, u0);
        acc_row16(acc, u1);
        acc_row16(acc, u2);
        acc_row16(acc, u3);
    }
    for (; k < cnt; ++k) {
        int s0 = edge_src[start + k];
        acc_row16(acc, *(const uint4*)(Hp + ((size_t)s0 << 6) + (l << 3)));
    }

    float dv = dinv[node];
    const float* bp = b + (l << 3);
    float* op = out + ((size_t)node << 6) + (l << 3);
    float4 o0, o1;
    o0.x = fmaxf(fmaf(acc[0].x, dv, bp[0]), 0.0f);
    o0.y = fmaxf(fmaf(acc[0].y, dv, bp[1]), 0.0f);
    o0.z = fmaxf(fmaf(acc[1].x, dv, bp[2]), 0.0f);
    o0.w = fmaxf(fmaf(acc[1].y, dv, bp[3]), 0.0f);
    o1.x = fmaxf(fmaf(acc[2].x, dv, bp[4]), 0.0f);
    o1.y = fmaxf(fmaf(acc[2].y, dv, bp[5]), 0.0f);
    o1.z = fmaxf(fmaf(acc[3].x, dv, bp[6]), 0.0f);
    o1.w = fmaxf(fmaf(acc[3].y, dv, bp[7]), 0.0f);
    *(float4*)op = o0;
    *(float4*)(op + 4) = o1;
}

extern "C" void kernel_launch(void* const* d_in, const int* in_sizes, int n_in,
                              void* d_out, int out_size, void* d_ws, size_t ws_size,
                              hipStream_t stream) {
    const float* x  = (const float*)d_in[0];
    const int*   ei = (const int*)d_in[1];   // [2, E] int32
    const float* W1 = (const float*)d_in[2];
    const float* b1 = (const float*)d_in[3];
    const float* W2 = (const float*)d_in[4];
    const float* b2 = (const float*)d_in[5];
    float* out = (float*)d_out;

    const int n_feat  = 128;
    const int n_nodes = in_sizes[0] / n_feat;   // 50000
    const int n_edges = in_sizes[1] / 2;        // 800000
    const int* src = ei;
    const int* dst = ei + n_edges;
    const int nbins = (n_nodes + 63) >> 6;      // 782 (<= 1023)

    // workspace layout (4B units, 16B-aligned chunks)
    const size_t n_pad = (size_t)((n_nodes + 63) & ~63);
    float* dinv        = (float*)d_ws;                   // n_pad
    int*   degi        = (int*)(dinv + n_pad);           // n_pad
    int*   offsets     = degi + n_pad;                   // n_pad
    int*   bincnt      = offsets + n_pad;                // 1024
    int*   bin_base    = bincnt + 1024;                  // 1024 + sentinel
    int*   bin_cursor  = bin_base + 1040;                // 1024
    const size_t e_pad = (size_t)((n_edges + 63) & ~63);
    unsigned int* edge_binned = (unsigned int*)(bin_cursor + 1024);  // e_pad
    int*   edge_src    = (int*)(edge_binned + e_pad);    // e_pad
    __half* h          = (__half*)(edge_src + e_pad);    // n_nodes*64 fp16

    // ---- preprocessing (once per call; reused by both layers) ----
    k_zero<<<1, THREADS, 0, stream>>>((int4*)bincnt, 256);
    k_bin_count<<<(n_edges + 4095) / 4096, THREADS, 0, stream>>>(dst, bincnt, n_edges);
    k_bin_scan<<<1, 1024, 0, stream>>>(bincnt, bin_base, bin_cursor, nbins);
    k_bin_scatter<<<(n_edges + 4095) / 4096, 1024, 0, stream>>>(
        src, dst, bin_cursor, edge_binned, n_edges);
    k_csr_build<<<nbins, THREADS, 0, stream>>>(
        edge_binned, bin_base, edge_src, offsets, degi, dinv, n_nodes);

    const int gemm_blocks = (n_nodes + 63) / 64;
    const int agg_blocks = (n_nodes + (THREADS / 8) - 1) / (THREADS / 8);

    // ---- layer 1 ----
    k_gemm<128><<<gemm_blocks, THREADS, 0, stream>>>(x, W1, dinv, h, n_nodes);
    k_gather_agg<<<agg_blocks, THREADS, 0, stream>>>(
        h, offsets, degi, edge_src, dinv, b1, out, n_nodes);

    // ---- layer 2 ----
    k_gemm<64><<<gemm_blocks, THREADS, 0, stream>>>(out, W2, dinv, h, n_nodes);
    k_gather_agg<<<agg_blocks, THREADS, 0, stream>>>(
        h, offsets, degi, edge_src, dinv, b2, out, n_nodes);
}

// Round 11
// 103.520 us; speedup vs baseline: 7.7532x; 1.1266x over previous
//
#include <hip/hip_runtime.h>
#include <hip/hip_bf16.h>
#include <hip/hip_fp16.h>

// ---------------------------------------------------------------------------
// 2-layer GCN (PyG GCNConv semantics) on MI355X.
//   out[d] = relu( dinv[d]*( sum_e H'[src_e] + H'[d] ) + b ),  H' = dinv .* (X@W)
// R1..R9: CSR-gather; binned scatter; register-tiled GEMM; fused preprocess.
// R9->R10: H' stored fp16 (halves gather fetch). 116us.
// R10->R11: (a) fuse layer1-gather + layer2-GEMM (32-node tile in LDS;
//           layer-1 output never materialized); (b) wave-shfl scans in
//           bin_scatter/bin_scan (20 barriers -> 2).
// ---------------------------------------------------------------------------

#define THREADS 256

__device__ inline int wave_incl_scan(int v, int lane) {
#pragma unroll
    for (int ofs = 1; ofs < 64; ofs <<= 1) {
        int t = __shfl_up(v, ofs, 64);
        if (lane >= ofs) v += t;
    }
    return v;
}

// --- tiny zero (bincnt only, 1024 ints) ------------------------------------
__global__ void k_zero(int4* __restrict__ p, int n4) {
    int i = blockIdx.x * blockDim.x + threadIdx.x;
    if (i < n4) p[i] = make_int4(0, 0, 0, 0);
}

// --- per-bin histogram of dst (64-row bins), LDS-aggregated ----------------
__global__ __launch_bounds__(256)
void k_bin_count(const int* __restrict__ dst, int* __restrict__ bincnt,
                 int n_edges) {
    __shared__ int hist[1024];
    const int tid = threadIdx.x;
    for (int i = tid; i < 1024; i += 256) hist[i] = 0;
    __syncthreads();
    const int base = blockIdx.x * 4096 + tid * 16;
#pragma unroll
    for (int j = 0; j < 4; ++j) {
        int o = base + j * 4;
        if (o + 4 <= n_edges) {
            int4 d = *(const int4*)&dst[o];
            atomicAdd(&hist[d.x >> 6], 1);
            atomicAdd(&hist[d.y >> 6], 1);
            atomicAdd(&hist[d.z >> 6], 1);
            atomicAdd(&hist[d.w >> 6], 1);
        } else {
            for (int t = o; t < n_edges; ++t) atomicAdd(&hist[dst[t] >> 6], 1);
        }
    }
    __syncthreads();
    for (int i = tid; i < 1024; i += 256)
        if (hist[i]) atomicAdd(&bincnt[i], hist[i]);
}

// --- single-block scan over bins (shfl-based) ------------------------------
__global__ __launch_bounds__(1024)
void k_bin_scan(const int* __restrict__ bincnt, int* __restrict__ bin_base,
                int* __restrict__ bin_cursor, int nbins) {
    __shared__ int wsum[16];
    const int tid = threadIdx.x;
    const int lane = tid & 63;
    const int wid = tid >> 6;
    int v = (tid < nbins) ? bincnt[tid] : 0;
    int s = wave_incl_scan(v, lane);
    if (lane == 63) wsum[wid] = s;
    __syncthreads();
    if (wid == 0) {
        int t = (lane < 16) ? wsum[lane] : 0;
        int t2 = wave_incl_scan(t, lane);
        if (lane < 16) wsum[lane] = t2;
    }
    __syncthreads();
    int incl = s + ((wid > 0) ? wsum[wid - 1] : 0);
    if (tid < nbins) {
        int excl = incl - v;
        bin_base[tid] = excl;
        bin_cursor[tid] = excl;
    }
    if (tid == 0) bin_base[nbins] = wsum[15];
}

// --- pass 1: bin edges by 64-row dst-bin, coalesced writes -----------------
// 1024 threads x 4 edges = 4096 edges/block. packed = (src<<6) | (dst & 63).
__global__ __launch_bounds__(1024)
void k_bin_scatter(const int* __restrict__ src, const int* __restrict__ dst,
                   int* __restrict__ bin_cursor, unsigned int* __restrict__ edge_binned,
                   int n_edges) {
    __shared__ int cnt[1024];
    __shared__ int lbase[1024];
    __shared__ int gbase[1024];
    __shared__ int run[1024];
    __shared__ int wsum[16];
    __shared__ unsigned int staged[4096];
    __shared__ unsigned short binarr[4096];
    const int tid = threadIdx.x;
    const int lane = tid & 63;
    const int wid = tid >> 6;
    const int base = blockIdx.x * 4096 + tid * 4;
    cnt[tid] = 0;
    run[tid] = 0;
    __syncthreads();

    int dv[4], sv[4];
    int nv = (base < n_edges) ? min(4, n_edges - base) : 0;
    if (nv == 4) {
        int4 a = *(const int4*)&dst[base];
        dv[0] = a.x; dv[1] = a.y; dv[2] = a.z; dv[3] = a.w;
        int4 b = *(const int4*)&src[base];
        sv[0] = b.x; sv[1] = b.y; sv[2] = b.z; sv[3] = b.w;
    } else {
        for (int j = 0; j < nv; ++j) {
            dv[j] = dst[base + j];
            sv[j] = src[base + j];
        }
    }
    for (int j = 0; j < nv; ++j) atomicAdd(&cnt[dv[j] >> 6], 1);
    __syncthreads();
    int mycnt = cnt[tid];
    // shfl-based inclusive scan of 1024 per-bin counts
    int s = wave_incl_scan(mycnt, lane);
    if (lane == 63) wsum[wid] = s;
    __syncthreads();
    if (wid == 0) {
        int t = (lane < 16) ? wsum[lane] : 0;
        int t2 = wave_incl_scan(t, lane);
        if (lane < 16) wsum[lane] = t2;
    }
    __syncthreads();
    int incl = s + ((wid > 0) ? wsum[wid - 1] : 0);
    lbase[tid] = incl - mycnt;
    if (mycnt > 0) gbase[tid] = atomicAdd(&bin_cursor[tid], mycnt);
    __syncthreads();
    for (int j = 0; j < nv; ++j) {
        int bn = dv[j] >> 6;
        int rank = atomicAdd(&run[bn], 1);
        int lp = lbase[bn] + rank;
        staged[lp] = ((unsigned)sv[j] << 6) | (unsigned)(dv[j] & 63);
        binarr[lp] = (unsigned short)bn;
    }
    __syncthreads();
    int tot = wsum[15];
    for (int slot = tid; slot < tot; slot += 1024) {
        int bn = binarr[slot];
        edge_binned[gbase[bn] + (slot - lbase[bn])] = staged[slot];
    }
}

// --- pass 2: per-bin degree count + scan + exact CSR + node metadata -------
__global__ __launch_bounds__(256)
void k_csr_build(const unsigned int* __restrict__ edge_binned,
                 const int* __restrict__ bin_base, int* __restrict__ edge_src,
                 int* __restrict__ offsets, int* __restrict__ degi,
                 float* __restrict__ dinv, int n_nodes) {
    __shared__ int lcnt[64];
    __shared__ int sc[64];
    __shared__ int lcur[64];
    const int b = blockIdx.x;
    const int node0 = b << 6;
    const int tid = threadIdx.x;
    const int ebeg = bin_base[b];
    const int eend = bin_base[b + 1];

    if (tid < 64) lcnt[tid] = 0;
    __syncthreads();
    for (int k = ebeg + tid; k < eend; k += 256)
        atomicAdd(&lcnt[edge_binned[k] & 63u], 1);
    __syncthreads();

    if (tid < 64) sc[tid] = lcnt[tid];
    __syncthreads();
    for (int ofs = 1; ofs < 64; ofs <<= 1) {
        int v = 0;
        if (tid < 64 && tid >= ofs) v = sc[tid - ofs];
        __syncthreads();
        if (tid < 64) sc[tid] += v;
        __syncthreads();
    }
    if (tid < 64) {
        int cntv = lcnt[tid];
        int excl = ebeg + sc[tid] - cntv;
        lcur[tid] = excl;
        int node = node0 + tid;
        if (node < n_nodes) {
            offsets[node] = excl;
            degi[node] = cntv;
            dinv[node] = 1.0f / sqrtf((float)(1 + cntv));
        }
    }
    __syncthreads();
    for (int k = ebeg + tid; k < eend; k += 256) {
        unsigned p = edge_binned[k];
        int pos = atomicAdd(&lcur[p & 63u], 1);
        edge_src[pos] = (int)(p >> 6);
    }
}

// --- register-tiled GEMM: H'[r,:] = fp16( dinv[r] * (X[r,:K] @ W[K,64]) ) --
template <int K>
__global__ __launch_bounds__(256, 2)
void k_gemm(const float* __restrict__ X, const float* __restrict__ W,
            const float* __restrict__ dinv, __half* __restrict__ H, int n_rows) {
    constexpr int KQ = K / 4;
    constexpr int RSH = (KQ == 32) ? 5 : 4;
    __shared__ float sW[K * 64];
    __shared__ float sX[64 * K];
    const int tid = threadIdx.x;
    const int row0 = blockIdx.x * 64;

#pragma unroll
    for (int it = 0; it < (K * 64 / 4) / THREADS; ++it) {
        int idx = it * THREADS + tid;
        ((float4*)sW)[idx] = ((const float4*)W)[idx];
    }
#pragma unroll
    for (int it = 0; it < (64 * KQ) / THREADS; ++it) {
        int idx = it * THREADS + tid;
        int kq = idx & (KQ - 1);
        int r = idx >> RSH;
        float4 g = make_float4(0.f, 0.f, 0.f, 0.f);
        int grow = row0 + r;
        if (grow < n_rows) g = *(const float4*)&X[(size_t)grow * K + 4 * kq];
        *(float4*)&sX[r * K + ((kq ^ (r & 7)) << 2)] = g;
    }
    __syncthreads();

    const int tx = tid & 15;
    const int ty = tid >> 4;
    float acc[4][4];
#pragma unroll
    for (int i = 0; i < 4; ++i)
#pragma unroll
        for (int j = 0; j < 4; ++j) acc[i][j] = 0.f;

#pragma unroll 2
    for (int k4 = 0; k4 < KQ; ++k4) {
        float4 b0 = *(const float4*)&sW[(4 * k4 + 0) * 64 + 4 * tx];
        float4 b1 = *(const float4*)&sW[(4 * k4 + 1) * 64 + 4 * tx];
        float4 b2 = *(const float4*)&sW[(4 * k4 + 2) * 64 + 4 * tx];
        float4 b3 = *(const float4*)&sW[(4 * k4 + 3) * 64 + 4 * tx];
#pragma unroll
        for (int i = 0; i < 4; ++i) {
            int r = 4 * ty + i;
            float4 a = *(const float4*)&sX[r * K + ((k4 ^ (r & 7)) << 2)];
            acc[i][0] = fmaf(a.x, b0.x, acc[i][0]);
            acc[i][1] = fmaf(a.x, b0.y, acc[i][1]);
            acc[i][2] = fmaf(a.x, b0.z, acc[i][2]);
            acc[i][3] = fmaf(a.x, b0.w, acc[i][3]);
            acc[i][0] = fmaf(a.y, b1.x, acc[i][0]);
            acc[i][1] = fmaf(a.y, b1.y, acc[i][1]);
            acc[i][2] = fmaf(a.y, b1.z, acc[i][2]);
            acc[i][3] = fmaf(a.y, b1.w, acc[i][3]);
            acc[i][0] = fmaf(a.z, b2.x, acc[i][0]);
            acc[i][1] = fmaf(a.z, b2.y, acc[i][1]);
            acc[i][2] = fmaf(a.z, b2.z, acc[i][2]);
            acc[i][3] = fmaf(a.z, b2.w, acc[i][3]);
            acc[i][0] = fmaf(a.w, b3.x, acc[i][0]);
            acc[i][1] = fmaf(a.w, b3.y, acc[i][1]);
            acc[i][2] = fmaf(a.w, b3.z, acc[i][2]);
            acc[i][3] = fmaf(a.w, b3.w, acc[i][3]);
        }
    }

#pragma unroll
    for (int i = 0; i < 4; ++i) {
        int grow = row0 + 4 * ty + i;
        if (grow < n_rows) {
            float dvv = dinv[grow];
            union { __half2 h[2]; uint2 u; } pk;
            pk.h[0] = __floats2half2_rn(acc[i][0] * dvv, acc[i][1] * dvv);
            pk.h[1] = __floats2half2_rn(acc[i][2] * dvv, acc[i][3] * dvv);
            *(uint2*)&H[(size_t)grow * 64 + 4 * tx] = pk.u;
        }
    }
}

// --- fp16 row accumulate helper --------------------------------------------
__device__ inline void acc_row16(float2 acc[4], uint4 u) {
    const __half2* hp = (const __half2*)&u;
    float2 a = __half22float2(hp[0]);
    float2 b = __half22float2(hp[1]);
    float2 c = __half22float2(hp[2]);
    float2 d = __half22float2(hp[3]);
    acc[0].x += a.x; acc[0].y += a.y;
    acc[1].x += b.x; acc[1].y += b.y;
    acc[2].x += c.x; acc[2].y += c.y;
    acc[3].x += d.x; acc[3].y += d.y;
}

// gather one node's aggregate: acc = H'[node] + sum_e H'[src_e], half8 slot l
__device__ inline void gather_node(float2 acc[4], const __half* __restrict__ Hp,
                                   int node, int l, const int* __restrict__ offsets,
                                   const int* __restrict__ degi,
                                   const int* __restrict__ edge_src) {
    acc[0] = make_float2(0.f, 0.f); acc[1] = make_float2(0.f, 0.f);
    acc[2] = make_float2(0.f, 0.f); acc[3] = make_float2(0.f, 0.f);
    acc_row16(acc, *(const uint4*)(Hp + ((size_t)node << 6) + (l << 3)));  // self
    int start = offsets[node];
    int cnt = degi[node];
    int k = 0;
    for (; k + 8 <= cnt; k += 8) {
        int s0 = edge_src[start + k];
        int s1 = edge_src[start + k + 1];
        int s2 = edge_src[start + k + 2];
        int s3 = edge_src[start + k + 3];
        int s4 = edge_src[start + k + 4];
        int s5 = edge_src[start + k + 5];
        int s6 = edge_src[start + k + 6];
        int s7 = edge_src[start + k + 7];
        uint4 u0 = *(const uint4*)(Hp + ((size_t)s0 << 6) + (l << 3));
        uint4 u1 = *(const uint4*)(Hp + ((size_t)s1 << 6) + (l << 3));
        uint4 u2 = *(const uint4*)(Hp + ((size_t)s2 << 6) + (l << 3));
        uint4 u3 = *(const uint4*)(Hp + ((size_t)s3 << 6) + (l << 3));
        uint4 u4 = *(const uint4*)(Hp + ((size_t)s4 << 6) + (l << 3));
        uint4 u5 = *(const uint4*)(Hp + ((size_t)s5 << 6) + (l << 3));
        uint4 u6 = *(const uint4*)(Hp + ((size_t)s6 << 6) + (l << 3));
        uint4 u7 = *(const uint4*)(Hp + ((size_t)s7 << 6) + (l << 3));
        acc_row16(acc, u0); acc_row16(acc, u1); acc_row16(acc, u2); acc_row16(acc, u3);
        acc_row16(acc, u4); acc_row16(acc, u5); acc_row16(acc, u6); acc_row16(acc, u7);
    }
    for (; k + 4 <= cnt; k += 4) {
        int s0 = edge_src[start + k];
        int s1 = edge_src[start + k + 1];
        int s2 = edge_src[start + k + 2];
        int s3 = edge_src[start + k + 3];
        uint4 u0 = *(const uint4*)(Hp + ((size_t)s0 << 6) + (l << 3));
        uint4 u1 = *(const uint4*)(Hp + ((size_t)s1 << 6) + (l << 3));
        uint4 u2 = *(const uint4*)(Hp + ((size_t)s2 << 6) + (l << 3));
        uint4 u3 = *(const uint4*)(Hp + ((size_t)s3 << 6) + (l << 3));
        acc_row16(acc, u0); acc_row16(acc, u1); acc_row16(acc, u2); acc_row16(acc, u3);
    }
    for (; k < cnt; ++k) {
        int s0 = edge_src[start + k];
        acc_row16(acc, *(const uint4*)(Hp + ((size_t)s0 << 6) + (l << 3)));
    }
}

// --- fused: layer-1 gather+epilogue -> LDS tile -> layer-2 GEMM -> h2 fp16 -
// block = 256 threads = 32 nodes (8 lanes x half8 each).
__global__ __launch_bounds__(256)
void k_agg_gemm(const __half* __restrict__ Hp, const int* __restrict__ offsets,
                const int* __restrict__ degi, const int* __restrict__ edge_src,
                const float* __restrict__ dinv, const float* __restrict__ b1,
                const float* __restrict__ W2, __half* __restrict__ H2, int n_nodes) {
    __shared__ float sX[32 * 64];   // layer-1 output tile (swizzled)
    __shared__ float sW[64 * 64];   // W2
    const int tid = threadIdx.x;
    const int node0 = blockIdx.x * 32;

    // stage W2 (no dependency on gather)
#pragma unroll
    for (int it = 0; it < 4; ++it)
        ((float4*)sW)[it * 256 + tid] = ((const float4*)W2)[it * 256 + tid];

    // phase A: gather 32 nodes; apply layer-1 epilogue; write swizzled tile
    {
        const int r = tid >> 3;          // node_local 0..31
        const int l = tid & 7;           // half8 slot
        const int node = node0 + r;
        float v[8];
        if (node < n_nodes) {
            float2 acc[4];
            gather_node(acc, Hp, node, l, offsets, degi, edge_src);
            float dv = dinv[node];
            const float* bp = b1 + (l << 3);
            v[0] = fmaxf(fmaf(acc[0].x, dv, bp[0]), 0.f);
            v[1] = fmaxf(fmaf(acc[0].y, dv, bp[1]), 0.f);
            v[2] = fmaxf(fmaf(acc[1].x, dv, bp[2]), 0.f);
            v[3] = fmaxf(fmaf(acc[1].y, dv, bp[3]), 0.f);
            v[4] = fmaxf(fmaf(acc[2].x, dv, bp[4]), 0.f);
            v[5] = fmaxf(fmaf(acc[2].y, dv, bp[5]), 0.f);
            v[6] = fmaxf(fmaf(acc[3].x, dv, bp[6]), 0.f);
            v[7] = fmaxf(fmaf(acc[3].y, dv, bp[7]), 0.f);
        } else {
#pragma unroll
            for (int j = 0; j < 8; ++j) v[j] = 0.f;
        }
        // feats 8l..8l+7 = col-quads 2l, 2l+1; swizzle (kq ^ (r&7))<<2
        *(float4*)&sX[r * 64 + (((2 * l + 0) ^ (r & 7)) << 2)] =
            make_float4(v[0], v[1], v[2], v[3]);
        *(float4*)&sX[r * 64 + (((2 * l + 1) ^ (r & 7)) << 2)] =
            make_float4(v[4], v[5], v[6], v[7]);
    }
    __syncthreads();

    // phase B: 32x64x64 GEMM (2x4 outputs per thread)
    const int tx = tid & 15;
    const int ty = tid >> 4;
    float acc2[2][4];
#pragma unroll
    for (int i = 0; i < 2; ++i)
#pragma unroll
        for (int j = 0; j < 4; ++j) acc2[i][j] = 0.f;

#pragma unroll 2
    for (int k4 = 0; k4 < 16; ++k4) {
        float4 b0 = *(const float4*)&sW[(4 * k4 + 0) * 64 + 4 * tx];
        float4 b1v = *(const float4*)&sW[(4 * k4 + 1) * 64 + 4 * tx];
        float4 b2 = *(const float4*)&sW[(4 * k4 + 2) * 64 + 4 * tx];
        float4 b3 = *(const float4*)&sW[(4 * k4 + 3) * 64 + 4 * tx];
#pragma unroll
        for (int i = 0; i < 2; ++i) {
            int r = 2 * ty + i;
            float4 a = *(const float4*)&sX[r * 64 + ((k4 ^ (r & 7)) << 2)];
            acc2[i][0] = fmaf(a.x, b0.x, acc2[i][0]);
            acc2[i][1] = fmaf(a.x, b0.y, acc2[i][1]);
            acc2[i][2] = fmaf(a.x, b0.z, acc2[i][2]);
            acc2[i][3] = fmaf(a.x, b0.w, acc2[i][3]);
            acc2[i][0] = fmaf(a.y, b1v.x, acc2[i][0]);
            acc2[i][1] = fmaf(a.y, b1v.y, acc2[i][1]);
            acc2[i][2] = fmaf(a.y, b1v.z, acc2[i][2]);
            acc2[i][3] = fmaf(a.y, b1v.w, acc2[i][3]);
            acc2[i][0] = fmaf(a.z, b2.x, acc2[i][0]);
            acc2[i][1] = fmaf(a.z, b2.y, acc2[i][1]);
            acc2[i][2] = fmaf(a.z, b2.z, acc2[i][2]);
            acc2[i][3] = fmaf(a.z, b2.w, acc2[i][3]);
            acc2[i][0] = fmaf(a.w, b3.x, acc2[i][0]);
            acc2[i][1] = fmaf(a.w, b3.y, acc2[i][1]);
            acc2[i][2] = fmaf(a.w, b3.z, acc2[i][2]);
            acc2[i][3] = fmaf(a.w, b3.w, acc2[i][3]);
        }
    }

#pragma unroll
    for (int i = 0; i < 2; ++i) {
        int grow = node0 + 2 * ty + i;
        if (grow < n_nodes) {
            float dvv = dinv[grow];
            union { __half2 h[2]; uint2 u; } pk;
            pk.h[0] = __floats2half2_rn(acc2[i][0] * dvv, acc2[i][1] * dvv);
            pk.h[1] = __floats2half2_rn(acc2[i][2] * dvv, acc2[i][3] * dvv);
            *(uint2*)&H2[(size_t)grow * 64 + 4 * tx] = pk.u;
        }
    }
}

// --- final gather-aggregate + epilogue (fp16 rows, fp32 out) ---------------
__global__ void k_gather_agg(const __half* __restrict__ Hp, const int* __restrict__ offsets,
                             const int* __restrict__ degi, const int* __restrict__ edge_src,
                             const float* __restrict__ dinv, const float* __restrict__ b,
                             float* __restrict__ out, int n_nodes) {
    int node = blockIdx.x * (THREADS / 8) + (threadIdx.x >> 3);
    if (node >= n_nodes) return;
    int l = threadIdx.x & 7;
    float2 acc[4];
    gather_node(acc, Hp, node, l, offsets, degi, edge_src);

    float dv = dinv[node];
    const float* bp = b + (l << 3);
    float* op = out + ((size_t)node << 6) + (l << 3);
    float4 o0, o1;
    o0.x = fmaxf(fmaf(acc[0].x, dv, bp[0]), 0.0f);
    o0.y = fmaxf(fmaf(acc[0].y, dv, bp[1]), 0.0f);
    o0.z = fmaxf(fmaf(acc[1].x, dv, bp[2]), 0.0f);
    o0.w = fmaxf(fmaf(acc[1].y, dv, bp[3]), 0.0f);
    o1.x = fmaxf(fmaf(acc[2].x, dv, bp[4]), 0.0f);
    o1.y = fmaxf(fmaf(acc[2].y, dv, bp[5]), 0.0f);
    o1.z = fmaxf(fmaf(acc[3].x, dv, bp[6]), 0.0f);
    o1.w = fmaxf(fmaf(acc[3].y, dv, bp[7]), 0.0f);
    *(float4*)op = o0;
    *(float4*)(op + 4) = o1;
}

extern "C" void kernel_launch(void* const* d_in, const int* in_sizes, int n_in,
                              void* d_out, int out_size, void* d_ws, size_t ws_size,
                              hipStream_t stream) {
    const float* x  = (const float*)d_in[0];
    const int*   ei = (const int*)d_in[1];   // [2, E] int32
    const float* W1 = (const float*)d_in[2];
    const float* b1 = (const float*)d_in[3];
    const float* W2 = (const float*)d_in[4];
    const float* b2 = (const float*)d_in[5];
    float* out = (float*)d_out;

    const int n_feat  = 128;
    const int n_nodes = in_sizes[0] / n_feat;   // 50000
    const int n_edges = in_sizes[1] / 2;        // 800000
    const int* src = ei;
    const int* dst = ei + n_edges;
    const int nbins = (n_nodes + 63) >> 6;      // 782 (<= 1023)

    // workspace layout (4B units, 16B-aligned chunks)
    const size_t n_pad = (size_t)((n_nodes + 63) & ~63);
    float* dinv        = (float*)d_ws;                   // n_pad
    int*   degi        = (int*)(dinv + n_pad);           // n_pad
    int*   offsets     = degi + n_pad;                   // n_pad
    int*   bincnt      = offsets + n_pad;                // 1024
    int*   bin_base    = bincnt + 1024;                  // 1024 + sentinel
    int*   bin_cursor  = bin_base + 1040;                // 1024
    const size_t e_pad = (size_t)((n_edges + 63) & ~63);
    unsigned int* edge_binned = (unsigned int*)(bin_cursor + 1024);  // e_pad
    int*   edge_src    = (int*)(edge_binned + e_pad);    // e_pad
    __half* h1         = (__half*)(edge_src + e_pad);    // n_nodes*64 fp16
    __half* h2         = h1 + (size_t)n_nodes * 64;      // n_nodes*64 fp16

    // ---- preprocessing (once per call; reused by both layers) ----
    k_zero<<<1, THREADS, 0, stream>>>((int4*)bincnt, 256);
    k_bin_count<<<(n_edges + 4095) / 4096, THREADS, 0, stream>>>(dst, bincnt, n_edges);
    k_bin_scan<<<1, 1024, 0, stream>>>(bincnt, bin_base, bin_cursor, nbins);
    k_bin_scatter<<<(n_edges + 4095) / 4096, 1024, 0, stream>>>(
        src, dst, bin_cursor, edge_binned, n_edges);
    k_csr_build<<<nbins, THREADS, 0, stream>>>(
        edge_binned, bin_base, edge_src, offsets, degi, dinv, n_nodes);

    const int gemm_blocks = (n_nodes + 63) / 64;
    const int fuse_blocks = (n_nodes + 31) / 32;
    const int agg_blocks = (n_nodes + (THREADS / 8) - 1) / (THREADS / 8);

    // ---- layer 1 GEMM: h1 = fp16(dinv .* (x @ W1)) ----
    k_gemm<128><<<gemm_blocks, THREADS, 0, stream>>>(x, W1, dinv, h1, n_nodes);
    // ---- fused: layer-1 gather+relu -> layer-2 GEMM -> h2 ----
    k_agg_gemm<<<fuse_blocks, THREADS, 0, stream>>>(
        h1, offsets, degi, edge_src, dinv, b1, W2, h2, n_nodes);
    // ---- layer 2 gather + epilogue -> out ----
    k_gather_agg<<<agg_blocks, THREADS, 0, stream>>>(
        h2, offsets, degi, edge_src, dinv, b2, out, n_nodes);
}